// Round 1
// baseline (317.024 us; speedup 1.0000x reference)
//
#include <hip/hip_runtime.h>
#include <cstdint>
#include <math.h>

typedef __attribute__((ext_vector_type(8))) short short8;
typedef __attribute__((ext_vector_type(4))) float floatx4;

#define D_MODEL 1024
#define NHEAD   16
#define HDIM    64
#define BATCH   2
#define SEQ     2048
#define MTOT    (BATCH*SEQ)   /* 4096 */

// round-to-nearest-even f32 -> bf16 (bits in a short)
__device__ __forceinline__ short f2bf(float f) {
    union { float f; uint32_t u; } v; v.f = f;
    uint32_t u = v.u;
    uint32_t r = (u + 0x7fffu + ((u >> 16) & 1u)) >> 16;
    return (short)(uint16_t)r;
}

// async global->LDS, 16B per lane. LDS dest must be wave-uniform-base + lane*16.
__device__ __forceinline__ void async16(const short* g, short* l) {
    __builtin_amdgcn_global_load_lds((__attribute__((address_space(1))) void*)g,
                                     (__attribute__((address_space(3))) void*)l,
                                     16, 0, 0);
}

// ---------------------------------------------------------------- cast kernel
__global__ __launch_bounds__(256) void cast_bf16_kernel(const float* __restrict__ in,
                                                        short* __restrict__ out, int n8) {
    int i = blockIdx.x * 256 + threadIdx.x;
    if (i >= n8) return;
    const floatx4* p = (const floatx4*)(in + (size_t)i * 8);
    floatx4 a = p[0], b = p[1];
    short8 r;
    r[0]=f2bf(a[0]); r[1]=f2bf(a[1]); r[2]=f2bf(a[2]); r[3]=f2bf(a[3]);
    r[4]=f2bf(b[0]); r[5]=f2bf(b[1]); r[6]=f2bf(b[2]); r[7]=f2bf(b[3]);
    *(short8*)(out + (size_t)i * 8) = r;
}

// ---------------------------------------------------------------- QKV GEMM
// C[m][n] = sum_k X[m][k] * W[n][k]  (x @ W.T), M=4096, N=K=1024.
// 128x128 tile, BK=32, 4 waves each 64x64 (4x4 of 16x16 MFMA blocks).
// LDS tiles stored chunk-swizzled [kc][row][8] (kc = k-octet) so A/B-fragment
// ds_read_b128 is 2-way-conflict-free (free per m136).
// mode 0: Q -> (2v-1)*0.125*log2e ; mode 1: K -> 2v-1 ; mode 2: V -> v.
// Output layout: [(b*16+h)][seq][d] bf16.
__global__ __launch_bounds__(256) void qkv_gemm_kernel(
    const short* __restrict__ Xb,
    const short* __restrict__ Wqb, const short* __restrict__ Wkb, const short* __restrict__ Wvb,
    const float* __restrict__ bq, const float* __restrict__ bk, const float* __restrict__ bv,
    short* __restrict__ Qo, short* __restrict__ Ko, short* __restrict__ Vo)
{
    const int mode = blockIdx.z;
    const short* W    = (mode == 0) ? Wqb : (mode == 1) ? Wkb : Wvb;
    const float* bias = (mode == 0) ? bq  : (mode == 1) ? bk  : bv;
    short* out        = (mode == 0) ? Qo  : (mode == 1) ? Ko  : Vo;

    const int m_t = blockIdx.y * 128;
    const int n_t = blockIdx.x * 128;
    const int tid = threadIdx.x;
    const int lane = tid & 63, laneM = lane & 15, quad = lane >> 4;
    const int wave = tid >> 6;
    const int wm = (wave >> 1) * 64, wn = (wave & 1) * 64;

    __shared__ short la[4][128][8];   // [kc][m][8]
    __shared__ short lb[4][128][8];   // [kc][n][8]

    floatx4 acc[4][4];
#pragma unroll
    for (int mb = 0; mb < 4; mb++)
#pragma unroll
        for (int nb = 0; nb < 4; nb++) acc[mb][nb] = (floatx4){0.f,0.f,0.f,0.f};

    for (int k0 = 0; k0 < D_MODEL; k0 += 32) {
        __syncthreads();
        {
            int c = tid;
            async16(Xb + (size_t)(m_t + (c & 127)) * D_MODEL + k0 + (c >> 7) * 8, &la[0][0][0] + c * 8);
            c = tid + 256;
            async16(Xb + (size_t)(m_t + (c & 127)) * D_MODEL + k0 + (c >> 7) * 8, &la[0][0][0] + c * 8);
            c = tid;
            async16(W  + (size_t)(n_t + (c & 127)) * D_MODEL + k0 + (c >> 7) * 8, &lb[0][0][0] + c * 8);
            c = tid + 256;
            async16(W  + (size_t)(n_t + (c & 127)) * D_MODEL + k0 + (c >> 7) * 8, &lb[0][0][0] + c * 8);
        }
        __syncthreads();

        short8 af[4], bf[4];
#pragma unroll
        for (int mb = 0; mb < 4; mb++) af[mb] = *(const short8*)&la[quad][wm + mb*16 + laneM][0];
#pragma unroll
        for (int nb = 0; nb < 4; nb++) bf[nb] = *(const short8*)&lb[quad][wn + nb*16 + laneM][0];
#pragma unroll
        for (int mb = 0; mb < 4; mb++)
#pragma unroll
            for (int nb = 0; nb < 4; nb++)
                acc[mb][nb] = __builtin_amdgcn_mfma_f32_16x16x32_bf16(af[mb], bf[nb], acc[mb][nb], 0, 0, 0);
    }

    // epilogue: bias + transform, store head-split bf16
#pragma unroll
    for (int nb = 0; nb < 4; nb++) {
        const int col = n_t + wn + nb*16 + laneM;
        const float bb = bias[col];
        const int h = col >> 6, d = col & 63;
#pragma unroll
        for (int mb = 0; mb < 4; mb++) {
            const int row0 = m_t + wm + mb*16 + quad*4;
#pragma unroll
            for (int r = 0; r < 4; r++) {
                float v = acc[mb][nb][r] + bb;
                if (mode == 0)      v = (2.0f*v - 1.0f) * 0.18033688011112042f; // 0.125*log2(e)
                else if (mode == 1) v = 2.0f*v - 1.0f;
                const int m = row0 + r;
                const int bi = m >> 11, seq = m & 2047;
                out[((size_t)(bi*NHEAD + h) * SEQ + seq) * HDIM + d] = f2bf(v);
            }
        }
    }
}

// ---------------------------------------------------------------- output GEMM
// out[m][n] = sum_k O[m][k] * Wo[n][k] + bo[n], fp32 out.
__global__ __launch_bounds__(256) void out_gemm_kernel(
    const short* __restrict__ Ab, const short* __restrict__ Wb,
    const float* __restrict__ bias, float* __restrict__ out)
{
    const int m_t = blockIdx.y * 128;
    const int n_t = blockIdx.x * 128;
    const int tid = threadIdx.x;
    const int lane = tid & 63, laneM = lane & 15, quad = lane >> 4;
    const int wave = tid >> 6;
    const int wm = (wave >> 1) * 64, wn = (wave & 1) * 64;

    __shared__ short la[4][128][8];
    __shared__ short lb[4][128][8];

    floatx4 acc[4][4];
#pragma unroll
    for (int mb = 0; mb < 4; mb++)
#pragma unroll
        for (int nb = 0; nb < 4; nb++) acc[mb][nb] = (floatx4){0.f,0.f,0.f,0.f};

    for (int k0 = 0; k0 < D_MODEL; k0 += 32) {
        __syncthreads();
        {
            int c = tid;
            async16(Ab + (size_t)(m_t + (c & 127)) * D_MODEL + k0 + (c >> 7) * 8, &la[0][0][0] + c * 8);
            c = tid + 256;
            async16(Ab + (size_t)(m_t + (c & 127)) * D_MODEL + k0 + (c >> 7) * 8, &la[0][0][0] + c * 8);
            c = tid;
            async16(Wb + (size_t)(n_t + (c & 127)) * D_MODEL + k0 + (c >> 7) * 8, &lb[0][0][0] + c * 8);
            c = tid + 256;
            async16(Wb + (size_t)(n_t + (c & 127)) * D_MODEL + k0 + (c >> 7) * 8, &lb[0][0][0] + c * 8);
        }
        __syncthreads();

        short8 af[4], bf[4];
#pragma unroll
        for (int mb = 0; mb < 4; mb++) af[mb] = *(const short8*)&la[quad][wm + mb*16 + laneM][0];
#pragma unroll
        for (int nb = 0; nb < 4; nb++) bf[nb] = *(const short8*)&lb[quad][wn + nb*16 + laneM][0];
#pragma unroll
        for (int mb = 0; mb < 4; mb++)
#pragma unroll
            for (int nb = 0; nb < 4; nb++)
                acc[mb][nb] = __builtin_amdgcn_mfma_f32_16x16x32_bf16(af[mb], bf[nb], acc[mb][nb], 0, 0, 0);
    }

#pragma unroll
    for (int nb = 0; nb < 4; nb++) {
        const int col = n_t + wn + nb*16 + laneM;
        const float bb = bias[col];
#pragma unroll
        for (int mb = 0; mb < 4; mb++) {
            const int row0 = m_t + wm + mb*16 + quad*4;
#pragma unroll
            for (int r = 0; r < 4; r++)
                out[(size_t)(row0 + r) * D_MODEL + col] = acc[mb][nb][r] + bb;
        }
    }
}

// ---------------------------------------------------------------- V transpose
// Vb [bh][seq][d] -> Vt [bh][d][seq]
__global__ __launch_bounds__(256) void transpose_v_kernel(const short* __restrict__ Vb,
                                                          short* __restrict__ Vt)
{
    const int bh = blockIdx.y;
    const int s0 = blockIdx.x * 64;
    const int t = threadIdx.x;
    __shared__ short tile[64][72];
    {
        const int sr = t >> 2, d0 = (t & 3) * 16;
        const short* src = Vb + ((size_t)bh * SEQ + s0 + sr) * HDIM + d0;
        const short8 a = *(const short8*)src;
        const short8 b = *(const short8*)(src + 8);
        *(short8*)&tile[sr][d0]     = a;
        *(short8*)&tile[sr][d0 + 8] = b;
    }
    __syncthreads();
    {
        const int dr = t >> 2, ss = (t & 3) * 16;
        short8 w0, w1;
#pragma unroll
        for (int i = 0; i < 8; i++) { w0[i] = tile[ss + i][dr]; w1[i] = tile[ss + 8 + i][dr]; }
        short* dst = Vt + ((size_t)bh * HDIM + dr) * SEQ + s0 + ss;
        *(short8*)dst       = w0;
        *(short8*)(dst + 8) = w1;
    }
}

// ---------------------------------------------------------------- flash attention
// Q has 0.125*log2e folded in; K is bipolar; softmax done base-2.
// Block: 64 Q rows (16 per wave), loop over 64-key tiles.
// kt/vtl in LDS chunk-swizzled [kc][row][8]; P round-trips through padded
// per-wave LDS (pitch 72) to convert C-layout -> A-layout.
__global__ __launch_bounds__(256) void attn_kernel(const short* __restrict__ Qb,
                                                   const short* __restrict__ Kb,
                                                   const short* __restrict__ Vt,
                                                   short* __restrict__ Ob)
{
    const int bh = blockIdx.y;
    const int q0 = blockIdx.x * 64;
    const int tid = threadIdx.x;
    const int wave = tid >> 6, lane = tid & 63, laneM = lane & 15, quad = lane >> 4;

    __shared__ short kt[8][64][8];    // [kc = d-octet][krow][8]
    __shared__ short vtl[8][64][8];   // [kc = k-octet][d][8]
    __shared__ short plds[4][16][72]; // per-wave P tile, padded pitch

    const short* Qp = Qb + ((size_t)bh * SEQ + q0 + wave*16 + laneM) * HDIM + quad*8;
    const short8 qf0 = *(const short8*)Qp;
    const short8 qf1 = *(const short8*)(Qp + 32);

    const short* Kbase = Kb + (size_t)bh * SEQ * HDIM;
    const short* Vbase = Vt + (size_t)bh * HDIM * SEQ;

    floatx4 o[4];
#pragma unroll
    for (int db = 0; db < 4; db++) o[db] = (floatx4){0.f,0.f,0.f,0.f};
    float mi[4], li[4];
#pragma unroll
    for (int r = 0; r < 4; r++) { mi[r] = -INFINITY; li[r] = 0.f; }

    const int c1 = tid, c2 = tid + 256;
    for (int k0 = 0; k0 < SEQ; k0 += 64) {
        __syncthreads();
        async16(Kbase + (size_t)(k0 + (c1 & 63)) * HDIM + (c1 >> 6) * 8, &kt[0][0][0]  + c1 * 8);
        async16(Kbase + (size_t)(k0 + (c2 & 63)) * HDIM + (c2 >> 6) * 8, &kt[0][0][0]  + c2 * 8);
        async16(Vbase + (size_t)(c1 & 63) * SEQ + k0 + (c1 >> 6) * 8,    &vtl[0][0][0] + c1 * 8);
        async16(Vbase + (size_t)(c2 & 63) * SEQ + k0 + (c2 >> 6) * 8,    &vtl[0][0][0] + c2 * 8);
        __syncthreads();

        // S = Qb * Kb^T  (scale+log2e already folded into Q)
        floatx4 s[4];
#pragma unroll
        for (int kb = 0; kb < 4; kb++) {
            const short8 b0 = *(const short8*)&kt[quad][kb*16 + laneM][0];
            const short8 b1 = *(const short8*)&kt[4 + quad][kb*16 + laneM][0];
            floatx4 z = (floatx4){0.f,0.f,0.f,0.f};
            z = __builtin_amdgcn_mfma_f32_16x16x32_bf16(qf0, b0, z, 0, 0, 0);
            z = __builtin_amdgcn_mfma_f32_16x16x32_bf16(qf1, b1, z, 0, 0, 0);
            s[kb] = z;
        }

        // online softmax (base 2); rows quad*4+r, cols spread over 16-lane group
        float alpha[4];
#pragma unroll
        for (int r = 0; r < 4; r++) {
            float t = fmaxf(fmaxf(s[0][r], s[1][r]), fmaxf(s[2][r], s[3][r]));
            t = fmaxf(t, __shfl_xor(t, 1, 64));
            t = fmaxf(t, __shfl_xor(t, 2, 64));
            t = fmaxf(t, __shfl_xor(t, 4, 64));
            t = fmaxf(t, __shfl_xor(t, 8, 64));
            const float mn = fmaxf(mi[r], t);
            alpha[r] = exp2f(mi[r] - mn);
            mi[r] = mn;
            float rs = 0.f;
#pragma unroll
            for (int kb = 0; kb < 4; kb++) {
                const float p = exp2f(s[kb][r] - mn);
                s[kb][r] = p;
                rs += p;
            }
            rs += __shfl_xor(rs, 1, 64);
            rs += __shfl_xor(rs, 2, 64);
            rs += __shfl_xor(rs, 4, 64);
            rs += __shfl_xor(rs, 8, 64);
            li[r] = li[r] * alpha[r] + rs;
        }

        // P: C-layout -> LDS -> A-layout (bf16)
#pragma unroll
        for (int kb = 0; kb < 4; kb++)
#pragma unroll
            for (int r = 0; r < 4; r++)
                plds[wave][quad*4 + r][kb*16 + laneM] = f2bf(s[kb][r]);

        asm volatile("s_waitcnt lgkmcnt(0)" ::: "memory");

        const short8 p0 = *(const short8*)&plds[wave][laneM][quad*8];
        const short8 p1 = *(const short8*)&plds[wave][laneM][32 + quad*8];

        // O = O*alpha + P*V
#pragma unroll
        for (int db = 0; db < 4; db++) {
#pragma unroll
            for (int r = 0; r < 4; r++) o[db][r] *= alpha[r];
            const short8 v0 = *(const short8*)&vtl[quad][db*16 + laneM][0];
            const short8 v1 = *(const short8*)&vtl[4 + quad][db*16 + laneM][0];
            o[db] = __builtin_amdgcn_mfma_f32_16x16x32_bf16(p0, v0, o[db], 0, 0, 0);
            o[db] = __builtin_amdgcn_mfma_f32_16x16x32_bf16(p1, v1, o[db], 0, 0, 0);
        }
    }

    // epilogue: normalize, store to [b][seq][h][d] bf16
    const int b = bh >> 4, h = bh & 15;
#pragma unroll
    for (int r = 0; r < 4; r++) {
        const float inv = 1.0f / li[r];
        const int seq = q0 + wave*16 + quad*4 + r;
        const size_t base = ((size_t)(b * SEQ + seq)) * D_MODEL + h * HDIM + laneM;
#pragma unroll
        for (int db = 0; db < 4; db++)
            Ob[base + db*16] = f2bf(o[db][r] * inv);
    }
}

// ---------------------------------------------------------------- launch
extern "C" void kernel_launch(void* const* d_in, const int* in_sizes, int n_in,
                              void* d_out, int out_size, void* d_ws, size_t ws_size,
                              hipStream_t stream)
{
    const float* x  = (const float*)d_in[0];
    const float* Wq = (const float*)d_in[1];
    const float* bq = (const float*)d_in[2];
    const float* Wk = (const float*)d_in[3];
    const float* bk = (const float*)d_in[4];
    const float* Wv = (const float*)d_in[5];
    const float* bv = (const float*)d_in[6];
    const float* Wo = (const float*)d_in[7];
    const float* bo = (const float*)d_in[8];
    float* out = (float*)d_out;

    short* ws = (short*)d_ws;
    const size_t NX = (size_t)MTOT * D_MODEL;     // 4194304
    const size_t NW = (size_t)D_MODEL * D_MODEL;  // 1048576
    short* xb  = ws;
    short* wqb = xb  + NX;
    short* wkb = wqb + NW;
    short* wvb = wkb + NW;
    short* wob = wvb + NW;
    short* Qb  = wob + NW;
    short* Kb  = Qb  + NX;
    short* Vb  = Kb  + NX;
    short* Vt  = Vb  + NX;
    short* Ob  = Vt  + NX;

    cast_bf16_kernel<<<dim3((unsigned)(NX/8/256)), 256, 0, stream>>>(x,  xb,  (int)(NX/8));
    cast_bf16_kernel<<<dim3((unsigned)(NW/8/256)), 256, 0, stream>>>(Wq, wqb, (int)(NW/8));
    cast_bf16_kernel<<<dim3((unsigned)(NW/8/256)), 256, 0, stream>>>(Wk, wkb, (int)(NW/8));
    cast_bf16_kernel<<<dim3((unsigned)(NW/8/256)), 256, 0, stream>>>(Wv, wvb, (int)(NW/8));
    cast_bf16_kernel<<<dim3((unsigned)(NW/8/256)), 256, 0, stream>>>(Wo, wob, (int)(NW/8));

    qkv_gemm_kernel<<<dim3(8, 32, 3), 256, 0, stream>>>(xb, wqb, wkb, wvb, bq, bk, bv, Qb, Kb, Vb);
    transpose_v_kernel<<<dim3(32, 32), 256, 0, stream>>>(Vb, Vt);
    attn_kernel<<<dim3(32, 32), 256, 0, stream>>>(Qb, Kb, Vt, Ob);
    out_gemm_kernel<<<dim3(8, 32), 256, 0, stream>>>(Ob, wob, bo, out);
}

// Round 2
// 282.959 us; speedup vs baseline: 1.1204x; 1.1204x over previous
//
#include <hip/hip_runtime.h>
#include <cstdint>
#include <math.h>

typedef __attribute__((ext_vector_type(8))) short short8;
typedef __attribute__((ext_vector_type(4))) float floatx4;
typedef __attribute__((ext_vector_type(16))) float floatx16;

#define D_MODEL 1024
#define NHEAD   16
#define HDIM    64
#define BATCH   2
#define SEQ     2048
#define MTOT    (BATCH*SEQ)   /* 4096 */

// round-to-nearest-even f32 -> bf16 (bits in a short)
__device__ __forceinline__ short f2bf(float f) {
    union { float f; uint32_t u; } v; v.f = f;
    uint32_t u = v.u;
    uint32_t r = (u + 0x7fffu + ((u >> 16) & 1u)) >> 16;
    return (short)(uint16_t)r;
}

// async global->LDS, 16B per lane. LDS dest must be wave-uniform-base + lane*16.
__device__ __forceinline__ void async16(const short* g, short* l) {
    __builtin_amdgcn_global_load_lds((__attribute__((address_space(1))) void*)g,
                                     (__attribute__((address_space(3))) void*)l,
                                     16, 0, 0);
}

// ---------------------------------------------------------------- merged cast
// Segments (in 8-elem groups): x: 524288 | Wq,Wk,Wv,Wo: 131072 each.
__global__ __launch_bounds__(256) void cast_all_kernel(
    const float* __restrict__ x,  const float* __restrict__ Wq, const float* __restrict__ Wk,
    const float* __restrict__ Wv, const float* __restrict__ Wo,
    short* __restrict__ xb, short* __restrict__ wqb, short* __restrict__ wkb,
    short* __restrict__ wvb, short* __restrict__ wob)
{
    const int i = blockIdx.x * 256 + threadIdx.x;   // 8-elem group index
    const float* src; short* dst; int off;
    if (i < 524288) { src = x; dst = xb; off = i; }
    else {
        const int j = i - 524288;
        const int seg = j >> 17, o = j & 131071;
        src = (seg == 0) ? Wq : (seg == 1) ? Wk : (seg == 2) ? Wv : Wo;
        dst = (seg == 0) ? wqb : (seg == 1) ? wkb : (seg == 2) ? wvb : wob;
        off = o;
    }
    const floatx4* p = (const floatx4*)(src + (size_t)off * 8);
    floatx4 a = p[0], b = p[1];
    short8 r;
    r[0]=f2bf(a[0]); r[1]=f2bf(a[1]); r[2]=f2bf(a[2]); r[3]=f2bf(a[3]);
    r[4]=f2bf(b[0]); r[5]=f2bf(b[1]); r[6]=f2bf(b[2]); r[7]=f2bf(b[3]);
    *(short8*)(dst + (size_t)off * 8) = r;
}

// ---------------------------------------------------------------- QKV GEMM
// C[m][n] = sum_k X[m][k] * W[n][k]  (x @ W.T), M=4096, N=K=1024.
// mode 0: Q -> (2v-1)*0.125*log2e ; mode 1: K -> 2v-1 ; mode 2: V -> v.
// Output layout: [(b*16+h)][seq][d] bf16.
__global__ __launch_bounds__(256) void qkv_gemm_kernel(
    const short* __restrict__ Xb,
    const short* __restrict__ Wqb, const short* __restrict__ Wkb, const short* __restrict__ Wvb,
    const float* __restrict__ bq, const float* __restrict__ bk, const float* __restrict__ bv,
    short* __restrict__ Qo, short* __restrict__ Ko, short* __restrict__ Vo)
{
    const int mode = blockIdx.z;
    const short* W    = (mode == 0) ? Wqb : (mode == 1) ? Wkb : Wvb;
    const float* bias = (mode == 0) ? bq  : (mode == 1) ? bk  : bv;
    short* out        = (mode == 0) ? Qo  : (mode == 1) ? Ko  : Vo;

    const int m_t = blockIdx.y * 128;
    const int n_t = blockIdx.x * 128;
    const int tid = threadIdx.x;
    const int lane = tid & 63, laneM = lane & 15, quad = lane >> 4;
    const int wave = tid >> 6;
    const int wm = (wave >> 1) * 64, wn = (wave & 1) * 64;

    __shared__ short la[4][128][8];   // [kc][m][8]
    __shared__ short lb[4][128][8];   // [kc][n][8]

    floatx4 acc[4][4];
#pragma unroll
    for (int mb = 0; mb < 4; mb++)
#pragma unroll
        for (int nb = 0; nb < 4; nb++) acc[mb][nb] = (floatx4){0.f,0.f,0.f,0.f};

    for (int k0 = 0; k0 < D_MODEL; k0 += 32) {
        __syncthreads();
        {
            int c = tid;
            async16(Xb + (size_t)(m_t + (c & 127)) * D_MODEL + k0 + (c >> 7) * 8, &la[0][0][0] + c * 8);
            c = tid + 256;
            async16(Xb + (size_t)(m_t + (c & 127)) * D_MODEL + k0 + (c >> 7) * 8, &la[0][0][0] + c * 8);
            c = tid;
            async16(W  + (size_t)(n_t + (c & 127)) * D_MODEL + k0 + (c >> 7) * 8, &lb[0][0][0] + c * 8);
            c = tid + 256;
            async16(W  + (size_t)(n_t + (c & 127)) * D_MODEL + k0 + (c >> 7) * 8, &lb[0][0][0] + c * 8);
        }
        __syncthreads();

        short8 af[4], bf[4];
#pragma unroll
        for (int mb = 0; mb < 4; mb++) af[mb] = *(const short8*)&la[quad][wm + mb*16 + laneM][0];
#pragma unroll
        for (int nb = 0; nb < 4; nb++) bf[nb] = *(const short8*)&lb[quad][wn + nb*16 + laneM][0];
#pragma unroll
        for (int mb = 0; mb < 4; mb++)
#pragma unroll
            for (int nb = 0; nb < 4; nb++)
                acc[mb][nb] = __builtin_amdgcn_mfma_f32_16x16x32_bf16(af[mb], bf[nb], acc[mb][nb], 0, 0, 0);
    }

#pragma unroll
    for (int nb = 0; nb < 4; nb++) {
        const int col = n_t + wn + nb*16 + laneM;
        const float bb = bias[col];
        const int h = col >> 6, d = col & 63;
#pragma unroll
        for (int mb = 0; mb < 4; mb++) {
            const int row0 = m_t + wm + mb*16 + quad*4;
#pragma unroll
            for (int r = 0; r < 4; r++) {
                float v = acc[mb][nb][r] + bb;
                if (mode == 0)      v = (2.0f*v - 1.0f) * 0.18033688011112042f; // 0.125*log2(e)
                else if (mode == 1) v = 2.0f*v - 1.0f;
                const int m = row0 + r;
                const int bi = m >> 11, seq = m & 2047;
                out[((size_t)(bi*NHEAD + h) * SEQ + seq) * HDIM + d] = f2bf(v);
            }
        }
    }
}

// ---------------------------------------------------------------- output GEMM
__global__ __launch_bounds__(256) void out_gemm_kernel(
    const short* __restrict__ Ab, const short* __restrict__ Wb,
    const float* __restrict__ bias, float* __restrict__ out)
{
    const int m_t = blockIdx.y * 128;
    const int n_t = blockIdx.x * 128;
    const int tid = threadIdx.x;
    const int lane = tid & 63, laneM = lane & 15, quad = lane >> 4;
    const int wave = tid >> 6;
    const int wm = (wave >> 1) * 64, wn = (wave & 1) * 64;

    __shared__ short la[4][128][8];
    __shared__ short lb[4][128][8];

    floatx4 acc[4][4];
#pragma unroll
    for (int mb = 0; mb < 4; mb++)
#pragma unroll
        for (int nb = 0; nb < 4; nb++) acc[mb][nb] = (floatx4){0.f,0.f,0.f,0.f};

    for (int k0 = 0; k0 < D_MODEL; k0 += 32) {
        __syncthreads();
        {
            int c = tid;
            async16(Ab + (size_t)(m_t + (c & 127)) * D_MODEL + k0 + (c >> 7) * 8, &la[0][0][0] + c * 8);
            c = tid + 256;
            async16(Ab + (size_t)(m_t + (c & 127)) * D_MODEL + k0 + (c >> 7) * 8, &la[0][0][0] + c * 8);
            c = tid;
            async16(Wb + (size_t)(n_t + (c & 127)) * D_MODEL + k0 + (c >> 7) * 8, &lb[0][0][0] + c * 8);
            c = tid + 256;
            async16(Wb + (size_t)(n_t + (c & 127)) * D_MODEL + k0 + (c >> 7) * 8, &lb[0][0][0] + c * 8);
        }
        __syncthreads();

        short8 af[4], bf[4];
#pragma unroll
        for (int mb = 0; mb < 4; mb++) af[mb] = *(const short8*)&la[quad][wm + mb*16 + laneM][0];
#pragma unroll
        for (int nb = 0; nb < 4; nb++) bf[nb] = *(const short8*)&lb[quad][wn + nb*16 + laneM][0];
#pragma unroll
        for (int mb = 0; mb < 4; mb++)
#pragma unroll
            for (int nb = 0; nb < 4; nb++)
                acc[mb][nb] = __builtin_amdgcn_mfma_f32_16x16x32_bf16(af[mb], bf[nb], acc[mb][nb], 0, 0, 0);
    }

#pragma unroll
    for (int nb = 0; nb < 4; nb++) {
        const int col = n_t + wn + nb*16 + laneM;
        const float bb = bias[col];
#pragma unroll
        for (int mb = 0; mb < 4; mb++) {
            const int row0 = m_t + wm + mb*16 + quad*4;
#pragma unroll
            for (int r = 0; r < 4; r++)
                out[(size_t)(row0 + r) * D_MODEL + col] = acc[mb][nb][r] + bb;
        }
    }
}

// ---------------------------------------------------------------- V transpose
// Vb [bh][seq][d] -> Vt [bh][d][seq]
__global__ __launch_bounds__(256) void transpose_v_kernel(const short* __restrict__ Vb,
                                                          short* __restrict__ Vt)
{
    const int bh = blockIdx.y;
    const int s0 = blockIdx.x * 64;
    const int t = threadIdx.x;
    __shared__ short tile[64][72];
    {
        const int sr = t >> 2, d0 = (t & 3) * 16;
        const short* src = Vb + ((size_t)bh * SEQ + s0 + sr) * HDIM + d0;
        const short8 a = *(const short8*)src;
        const short8 b = *(const short8*)(src + 8);
        *(short8*)&tile[sr][d0]     = a;
        *(short8*)&tile[sr][d0 + 8] = b;
    }
    __syncthreads();
    {
        const int dr = t >> 2, ss = (t & 3) * 16;
        short8 w0, w1;
#pragma unroll
        for (int i = 0; i < 8; i++) { w0[i] = tile[ss + i][dr]; w1[i] = tile[ss + 8 + i][dr]; }
        short* dst = Vt + ((size_t)bh * HDIM + dr) * SEQ + s0 + ss;
        *(short8*)dst       = w0;
        *(short8*)(dst + 8) = w1;
    }
}

// ---------------------------------------------------------------- flash attention
// 32x32x16 MFMA; 2 waves x 32 Q-rows = 64 rows/block; 64-key tiles.
// No running max: scores (base-2; 0.125*log2e folded into Q) satisfy
// |s-32| << 126, so p = 2^(s-32) never over/underflows; softmax
// normalization cancels the constant. Row sums accumulate per-lane in
// registers; single cross-lane reduction in the epilogue.
__global__ __launch_bounds__(128) void attn_kernel(const short* __restrict__ Qb,
                                                   const short* __restrict__ Kb,
                                                   const short* __restrict__ Vt,
                                                   short* __restrict__ Ob)
{
    const int bh = blockIdx.y;
    const int q0 = blockIdx.x * 64;
    const int tid = threadIdx.x;
    const int wave = tid >> 6, lane = tid & 63;
    const int l31 = lane & 31, hi = lane >> 5;

    __shared__ short kt[8][64][8];    // [d-octet][key][8]
    __shared__ short vtl[8][64][8];   // [key-octet][d][8]
    __shared__ short plds[2][32][72]; // per-wave P tile, pitch 72 (conflict-free)

    // Q A-fragments (32x32x16): A[m=lane&31][k=(lane>>5)*8+j], k-step = 16
    const short* Qp = Qb + ((size_t)bh * SEQ + q0 + wave*32 + l31) * HDIM + hi*8;
    short8 qf[4];
#pragma unroll
    for (int ks = 0; ks < 4; ks++) qf[ks] = *(const short8*)(Qp + ks*16);

    const short* Kbase = Kb + (size_t)bh * SEQ * HDIM;
    const short* Vbase = Vt + (size_t)bh * HDIM * SEQ;

    floatx16 o0, o1;
#pragma unroll
    for (int r = 0; r < 16; r++) { o0[r] = 0.f; o1[r] = 0.f; }
    float rsum[16];
#pragma unroll
    for (int r = 0; r < 16; r++) rsum[r] = 0.f;

    for (int k0 = 0; k0 < SEQ; k0 += 64) {
        __syncthreads();
#pragma unroll
        for (int t = 0; t < 4; t++) {
            const int c = tid + t*128;
            async16(Kbase + (size_t)(k0 + (c & 63)) * HDIM + (c >> 6) * 8, &kt[0][0][0] + c * 8);
        }
#pragma unroll
        for (int t = 0; t < 4; t++) {
            const int c = tid + t*128;
            async16(Vbase + (size_t)(c & 63) * SEQ + k0 + (c >> 6) * 8, &vtl[0][0][0] + c * 8);
        }
        __syncthreads();

        // S = Q K^T : two 32x32 key-blocks
        floatx16 s0, s1;
#pragma unroll
        for (int r = 0; r < 16; r++) { s0[r] = 0.f; s1[r] = 0.f; }
#pragma unroll
        for (int ks = 0; ks < 4; ks++) {
            const short8 b0 = *(const short8*)&kt[ks*2 + hi][l31][0];
            const short8 b1 = *(const short8*)&kt[ks*2 + hi][32 + l31][0];
            s0 = __builtin_amdgcn_mfma_f32_32x32x16_bf16(qf[ks], b0, s0, 0, 0, 0);
            s1 = __builtin_amdgcn_mfma_f32_32x32x16_bf16(qf[ks], b1, s1, 0, 0, 0);
        }

        // p = 2^(s-32); accumulate row sums; store P to LDS (C-layout -> A-layout)
#pragma unroll
        for (int r = 0; r < 16; r++) {
            const float e0 = exp2f(s0[r] - 32.f);
            const float e1 = exp2f(s1[r] - 32.f);
            rsum[r] += e0 + e1;
            const int row = (r & 3) + 8*(r >> 2) + 4*hi;
            plds[wave][row][l31]      = f2bf(e0);
            plds[wave][row][32 + l31] = f2bf(e1);
        }

        asm volatile("s_waitcnt lgkmcnt(0)" ::: "memory");

        // O += P V : A = P[m=l31][k], B = V[k][n=d] from Vt
#pragma unroll
        for (int ks = 0; ks < 4; ks++) {
            const short8 pa = *(const short8*)&plds[wave][l31][ks*16 + hi*8];
            const short8 v0 = *(const short8*)&vtl[ks*2 + hi][l31][0];
            const short8 v1 = *(const short8*)&vtl[ks*2 + hi][32 + l31][0];
            o0 = __builtin_amdgcn_mfma_f32_32x32x16_bf16(pa, v0, o0, 0, 0, 0);
            o1 = __builtin_amdgcn_mfma_f32_32x32x16_bf16(pa, v1, o1, 0, 0, 0);
        }
    }

    // reduce row sums across the 32 key-columns (within hi-group)
#pragma unroll
    for (int r = 0; r < 16; r++) {
        float s = rsum[r];
        s += __shfl_xor(s, 1, 64);
        s += __shfl_xor(s, 2, 64);
        s += __shfl_xor(s, 4, 64);
        s += __shfl_xor(s, 8, 64);
        s += __shfl_xor(s, 16, 64);
        rsum[r] = s;
    }

    // epilogue: normalize, store to [b][seq][h][d] bf16
    const int b = bh >> 4, h = bh & 15;
#pragma unroll
    for (int r = 0; r < 16; r++) {
        const float inv = 1.0f / rsum[r];
        const int seq = q0 + wave*32 + (r & 3) + 8*(r >> 2) + 4*hi;
        short* dst = Ob + ((size_t)(b * SEQ + seq)) * D_MODEL + h * HDIM + l31;
        dst[0]  = f2bf(o0[r] * inv);
        dst[32] = f2bf(o1[r] * inv);
    }
}

// ---------------------------------------------------------------- launch
extern "C" void kernel_launch(void* const* d_in, const int* in_sizes, int n_in,
                              void* d_out, int out_size, void* d_ws, size_t ws_size,
                              hipStream_t stream)
{
    const float* x  = (const float*)d_in[0];
    const float* Wq = (const float*)d_in[1];
    const float* bq = (const float*)d_in[2];
    const float* Wk = (const float*)d_in[3];
    const float* bk = (const float*)d_in[4];
    const float* Wv = (const float*)d_in[5];
    const float* bv = (const float*)d_in[6];
    const float* Wo = (const float*)d_in[7];
    const float* bo = (const float*)d_in[8];
    float* out = (float*)d_out;

    short* ws = (short*)d_ws;
    const size_t NX = (size_t)MTOT * D_MODEL;     // 4194304
    const size_t NW = (size_t)D_MODEL * D_MODEL;  // 1048576
    short* xb  = ws;
    short* wqb = xb  + NX;
    short* wkb = wqb + NW;
    short* wvb = wkb + NW;
    short* wob = wvb + NW;
    short* Qb  = wob + NW;
    short* Kb  = Qb  + NX;
    short* Vb  = Kb  + NX;
    short* Vt  = Vb  + NX;
    short* Ob  = Vt  + NX;

    cast_all_kernel<<<dim3(4096), 256, 0, stream>>>(x, Wq, Wk, Wv, Wo, xb, wqb, wkb, wvb, wob);
    qkv_gemm_kernel<<<dim3(8, 32, 3), 256, 0, stream>>>(xb, wqb, wkb, wvb, bq, bk, bv, Qb, Kb, Vb);
    transpose_v_kernel<<<dim3(32, 32), 256, 0, stream>>>(Vb, Vt);
    attn_kernel<<<dim3(32, 32), 128, 0, stream>>>(Qb, Kb, Vt, Ob);
    out_gemm_kernel<<<dim3(8, 32), 256, 0, stream>>>(Ob, wob, bo, out);
}

// Round 3
// 270.580 us; speedup vs baseline: 1.1716x; 1.0457x over previous
//
#include <hip/hip_runtime.h>
#include <cstdint>
#include <math.h>

typedef __attribute__((ext_vector_type(8))) short short8;
typedef __attribute__((ext_vector_type(4))) float floatx4;
typedef __attribute__((ext_vector_type(16))) float floatx16;

#define D_MODEL 1024
#define NHEAD   16
#define HDIM    64
#define BATCH   2
#define SEQ     2048
#define MTOT    (BATCH*SEQ)   /* 4096 */

// round-to-nearest-even f32 -> bf16 (bits in a short)
__device__ __forceinline__ short f2bf(float f) {
    union { float f; uint32_t u; } v; v.f = f;
    uint32_t u = v.u;
    uint32_t r = (u + 0x7fffu + ((u >> 16) & 1u)) >> 16;
    return (short)(uint16_t)r;
}

// pack two f32 -> [bf16(a) lo | bf16(b) hi]
__device__ __forceinline__ unsigned pkbf(float a, float b) {
    union { float f; uint32_t u; } x, y; x.f = a; y.f = b;
    uint32_t ra = (x.u + 0x7fffu + ((x.u >> 16) & 1u)) >> 16;
    uint32_t rb = (y.u + 0x7fffu + ((y.u >> 16) & 1u)) & 0xffff0000u;
    return ra | rb;
}

// async global->LDS, 16B per lane. LDS dest must be wave-uniform base + lane*16.
__device__ __forceinline__ void async16(const short* g, short* l) {
    __builtin_amdgcn_global_load_lds((__attribute__((address_space(1))) void*)g,
                                     (__attribute__((address_space(3))) void*)l,
                                     16, 0, 0);
}

// ---------------------------------------------------------------- merged cast
__global__ __launch_bounds__(256) void cast_all_kernel(
    const float* __restrict__ x,  const float* __restrict__ Wq, const float* __restrict__ Wk,
    const float* __restrict__ Wv, const float* __restrict__ Wo,
    short* __restrict__ xb, short* __restrict__ wqb, short* __restrict__ wkb,
    short* __restrict__ wvb, short* __restrict__ wob)
{
    const int i = blockIdx.x * 256 + threadIdx.x;   // 8-elem group index
    const float* src; short* dst; int off;
    if (i < 524288) { src = x; dst = xb; off = i; }
    else {
        const int j = i - 524288;
        const int seg = j >> 17, o = j & 131071;
        src = (seg == 0) ? Wq : (seg == 1) ? Wk : (seg == 2) ? Wv : Wo;
        dst = (seg == 0) ? wqb : (seg == 1) ? wkb : (seg == 2) ? wvb : wob;
        off = o;
    }
    const floatx4* p = (const floatx4*)(src + (size_t)off * 8);
    floatx4 a = p[0], b = p[1];
    short8 r;
    r[0]=f2bf(a[0]); r[1]=f2bf(a[1]); r[2]=f2bf(a[2]); r[3]=f2bf(a[3]);
    r[4]=f2bf(b[0]); r[5]=f2bf(b[1]); r[6]=f2bf(b[2]); r[7]=f2bf(b[3]);
    *(short8*)(dst + (size_t)off * 8) = r;
}

// ---------------------------------------------------------------- QKV GEMM
__global__ __launch_bounds__(256) void qkv_gemm_kernel(
    const short* __restrict__ Xb,
    const short* __restrict__ Wqb, const short* __restrict__ Wkb, const short* __restrict__ Wvb,
    const float* __restrict__ bq, const float* __restrict__ bk, const float* __restrict__ bv,
    short* __restrict__ Qo, short* __restrict__ Ko, short* __restrict__ Vo)
{
    const int mode = blockIdx.z;
    const short* W    = (mode == 0) ? Wqb : (mode == 1) ? Wkb : Wvb;
    const float* bias = (mode == 0) ? bq  : (mode == 1) ? bk  : bv;
    short* out        = (mode == 0) ? Qo  : (mode == 1) ? Ko  : Vo;

    const int m_t = blockIdx.y * 128;
    const int n_t = blockIdx.x * 128;
    const int tid = threadIdx.x;
    const int lane = tid & 63, laneM = lane & 15, quad = lane >> 4;
    const int wave = tid >> 6;
    const int wm = (wave >> 1) * 64, wn = (wave & 1) * 64;

    __shared__ short la[4][128][8];
    __shared__ short lb[4][128][8];

    floatx4 acc[4][4];
#pragma unroll
    for (int mb = 0; mb < 4; mb++)
#pragma unroll
        for (int nb = 0; nb < 4; nb++) acc[mb][nb] = (floatx4){0.f,0.f,0.f,0.f};

    for (int k0 = 0; k0 < D_MODEL; k0 += 32) {
        __syncthreads();
        {
            int c = tid;
            async16(Xb + (size_t)(m_t + (c & 127)) * D_MODEL + k0 + (c >> 7) * 8, &la[0][0][0] + c * 8);
            c = tid + 256;
            async16(Xb + (size_t)(m_t + (c & 127)) * D_MODEL + k0 + (c >> 7) * 8, &la[0][0][0] + c * 8);
            c = tid;
            async16(W  + (size_t)(n_t + (c & 127)) * D_MODEL + k0 + (c >> 7) * 8, &lb[0][0][0] + c * 8);
            c = tid + 256;
            async16(W  + (size_t)(n_t + (c & 127)) * D_MODEL + k0 + (c >> 7) * 8, &lb[0][0][0] + c * 8);
        }
        __syncthreads();

        short8 af[4], bf[4];
#pragma unroll
        for (int mb = 0; mb < 4; mb++) af[mb] = *(const short8*)&la[quad][wm + mb*16 + laneM][0];
#pragma unroll
        for (int nb = 0; nb < 4; nb++) bf[nb] = *(const short8*)&lb[quad][wn + nb*16 + laneM][0];
#pragma unroll
        for (int mb = 0; mb < 4; mb++)
#pragma unroll
            for (int nb = 0; nb < 4; nb++)
                acc[mb][nb] = __builtin_amdgcn_mfma_f32_16x16x32_bf16(af[mb], bf[nb], acc[mb][nb], 0, 0, 0);
    }

#pragma unroll
    for (int nb = 0; nb < 4; nb++) {
        const int col = n_t + wn + nb*16 + laneM;
        const float bb = bias[col];
        const int h = col >> 6, d = col & 63;
#pragma unroll
        for (int mb = 0; mb < 4; mb++) {
            const int row0 = m_t + wm + mb*16 + quad*4;
#pragma unroll
            for (int r = 0; r < 4; r++) {
                float v = acc[mb][nb][r] + bb;
                if (mode == 0)      v = (2.0f*v - 1.0f) * 0.18033688011112042f; // 0.125*log2(e)
                else if (mode == 1) v = 2.0f*v - 1.0f;
                const int m = row0 + r;
                const int bi = m >> 11, seq = m & 2047;
                out[((size_t)(bi*NHEAD + h) * SEQ + seq) * HDIM + d] = f2bf(v);
            }
        }
    }
}

// ---------------------------------------------------------------- output GEMM
__global__ __launch_bounds__(256) void out_gemm_kernel(
    const short* __restrict__ Ab, const short* __restrict__ Wb,
    const float* __restrict__ bias, float* __restrict__ out)
{
    const int m_t = blockIdx.y * 128;
    const int n_t = blockIdx.x * 128;
    const int tid = threadIdx.x;
    const int lane = tid & 63, laneM = lane & 15, quad = lane >> 4;
    const int wave = tid >> 6;
    const int wm = (wave >> 1) * 64, wn = (wave & 1) * 64;

    __shared__ short la[4][128][8];
    __shared__ short lb[4][128][8];

    floatx4 acc[4][4];
#pragma unroll
    for (int mb = 0; mb < 4; mb++)
#pragma unroll
        for (int nb = 0; nb < 4; nb++) acc[mb][nb] = (floatx4){0.f,0.f,0.f,0.f};

    for (int k0 = 0; k0 < D_MODEL; k0 += 32) {
        __syncthreads();
        {
            int c = tid;
            async16(Ab + (size_t)(m_t + (c & 127)) * D_MODEL + k0 + (c >> 7) * 8, &la[0][0][0] + c * 8);
            c = tid + 256;
            async16(Ab + (size_t)(m_t + (c & 127)) * D_MODEL + k0 + (c >> 7) * 8, &la[0][0][0] + c * 8);
            c = tid;
            async16(Wb + (size_t)(n_t + (c & 127)) * D_MODEL + k0 + (c >> 7) * 8, &lb[0][0][0] + c * 8);
            c = tid + 256;
            async16(Wb + (size_t)(n_t + (c & 127)) * D_MODEL + k0 + (c >> 7) * 8, &lb[0][0][0] + c * 8);
        }
        __syncthreads();

        short8 af[4], bf[4];
#pragma unroll
        for (int mb = 0; mb < 4; mb++) af[mb] = *(const short8*)&la[quad][wm + mb*16 + laneM][0];
#pragma unroll
        for (int nb = 0; nb < 4; nb++) bf[nb] = *(const short8*)&lb[quad][wn + nb*16 + laneM][0];
#pragma unroll
        for (int mb = 0; mb < 4; mb++)
#pragma unroll
            for (int nb = 0; nb < 4; nb++)
                acc[mb][nb] = __builtin_amdgcn_mfma_f32_16x16x32_bf16(af[mb], bf[nb], acc[mb][nb], 0, 0, 0);
    }

#pragma unroll
    for (int nb = 0; nb < 4; nb++) {
        const int col = n_t + wn + nb*16 + laneM;
        const float bb = bias[col];
#pragma unroll
        for (int mb = 0; mb < 4; mb++) {
            const int row0 = m_t + wm + mb*16 + quad*4;
#pragma unroll
            for (int r = 0; r < 4; r++)
                out[(size_t)(row0 + r) * D_MODEL + col] = acc[mb][nb][r] + bb;
        }
    }
}

// ---------------------------------------------------------------- V transpose
__global__ __launch_bounds__(256) void transpose_v_kernel(const short* __restrict__ Vb,
                                                          short* __restrict__ Vt)
{
    const int bh = blockIdx.y;
    const int s0 = blockIdx.x * 64;
    const int t = threadIdx.x;
    __shared__ short tile[64][72];
    {
        const int sr = t >> 2, d0 = (t & 3) * 16;
        const short* src = Vb + ((size_t)bh * SEQ + s0 + sr) * HDIM + d0;
        const short8 a = *(const short8*)src;
        const short8 b = *(const short8*)(src + 8);
        *(short8*)&tile[sr][d0]     = a;
        *(short8*)&tile[sr][d0 + 8] = b;
    }
    __syncthreads();
    {
        const int dr = t >> 2, ss = (t & 3) * 16;
        short8 w0, w1;
#pragma unroll
        for (int i = 0; i < 8; i++) { w0[i] = tile[ss + i][dr]; w1[i] = tile[ss + 8 + i][dr]; }
        short* dst = Vt + ((size_t)bh * HDIM + dr) * SEQ + s0 + ss;
        *(short8*)dst       = w0;
        *(short8*)(dst + 8) = w1;
    }
}

// ---------------------------------------------------------------- flash attention
// S computed TRANSPOSED: S^T = mfma(A=K_frag, B=Q_frag) -> C-layout lane = q,
// regs = keys. Softmax is pure per-lane math (rsum = 1 scalar/lane).
// P A-fragments for PV built IN-REGISTER: pack adjacent-k pairs to bf16x2
// (consecutive r in a quad = consecutive k), then one shfl_xor(32)+cndmask
// per (p_i,p_{i+2}) pair fixes the hi-half k-window mismatch
// (C: k=(r&3)+8(r>>2)+4hi  vs  A: k=8hi+2j+{0,1}).
// Double-buffered K/V staging: prefetch tile t+1 during compute of tile t.
// 4 waves x 32 q-rows = 128 q-rows/block.
__global__ __launch_bounds__(256) void attn_kernel(const short* __restrict__ Qb,
                                                   const short* __restrict__ Kb,
                                                   const short* __restrict__ Vt,
                                                   short* __restrict__ Ob)
{
    const int bh = blockIdx.y;
    const int q0 = blockIdx.x * 128;
    const int tid = threadIdx.x;
    const int wave = tid >> 6, lane = tid & 63;
    const int l31 = lane & 31;
    const bool hi = (lane >> 5) != 0;

    __shared__ short kt[2][8][64][8];    // [buf][d-octet][key][8]
    __shared__ short vtl[2][8][64][8];   // [buf][key-octet][d][8]

    const short* Kbase = Qb ? Kb + (size_t)bh * SEQ * HDIM : nullptr;
    const short* Vbase = Vt + (size_t)bh * HDIM * SEQ;

    // Q fragments (used as MFMA B operand: B[k=d][n=q], lane n = q)
    const short* Qp = Qb + ((size_t)bh * SEQ + q0 + wave*32 + l31) * HDIM + (hi ? 8 : 0);
    short8 qf[4];
#pragma unroll
    for (int ks = 0; ks < 4; ks++) qf[ks] = *(const short8*)(Qp + ks*16);

    floatx16 o0, o1;
#pragma unroll
    for (int r = 0; r < 16; r++) { o0[r] = 0.f; o1[r] = 0.f; }
    float rsum = 0.f;

    // stage tile (64 keys) at key-offset kk into buffer nb
#define STAGE(nb, kk)                                                                   \
    {                                                                                   \
        int c = tid;                                                                    \
        async16(Kbase + (size_t)((kk) + (c & 63)) * HDIM + (c >> 6) * 8,                \
                &kt[nb][0][0][0] + c * 8);                                              \
        c = tid + 256;                                                                  \
        async16(Kbase + (size_t)((kk) + (c & 63)) * HDIM + (c >> 6) * 8,                \
                &kt[nb][0][0][0] + c * 8);                                              \
        c = tid;                                                                        \
        async16(Vbase + (size_t)(c & 63) * SEQ + (kk) + (c >> 6) * 8,                   \
                &vtl[nb][0][0][0] + c * 8);                                             \
        c = tid + 256;                                                                  \
        async16(Vbase + (size_t)(c & 63) * SEQ + (kk) + (c >> 6) * 8,                   \
                &vtl[nb][0][0][0] + c * 8);                                             \
    }

    STAGE(0, 0)

    for (int t = 0; t < 32; ++t) {
        const int buf = t & 1;
        __syncthreads();                       // drains prefetch -> buf[t] ready
        STAGE(buf ^ 1, ((t + 1) & 31) * 64)    // prefetch next (wraps harmlessly)

        // S^T: D[m=key][n=q]
        floatx16 s0, s1;
#pragma unroll
        for (int r = 0; r < 16; r++) { s0[r] = 0.f; s1[r] = 0.f; }
#pragma unroll
        for (int ks = 0; ks < 4; ks++) {
            const short8 a0 = *(const short8*)&kt[buf][2*ks + hi][l31][0];
            const short8 a1 = *(const short8*)&kt[buf][2*ks + hi][32 + l31][0];
            s0 = __builtin_amdgcn_mfma_f32_32x32x16_bf16(a0, qf[ks], s0, 0, 0, 0);
            s1 = __builtin_amdgcn_mfma_f32_32x32x16_bf16(a1, qf[ks], s1, 0, 0, 0);
        }

        // p = 2^(s-32) (fixed offset; softmax normalization cancels it),
        // per-lane rsum, pack adjacent-k pairs
        unsigned p[16];
#pragma unroll
        for (int i = 0; i < 8; i++) {
            const float a0 = exp2f(s0[2*i] - 32.f), b0 = exp2f(s0[2*i+1] - 32.f);
            const float a1 = exp2f(s1[2*i] - 32.f), b1 = exp2f(s1[2*i+1] - 32.f);
            rsum += (a0 + b0) + (a1 + b1);
            p[i]     = pkbf(a0, b0);
            p[8 + i] = pkbf(a1, b1);
        }

        // build A-fragments: one shuffle serves both slots of a (pa,pb) pair
        unsigned fu[4][4];
#pragma unroll
        for (int g = 0; g < 4; g++) {          // g: frag index (ks)
            const int base = (g >> 1) * 8 + (g & 1) * 4;  // 0,4,8,12
#pragma unroll
            for (int j = 0; j < 2; j++) {
                const unsigned pa = p[base + j], pb = p[base + j + 2];
                const unsigned pre = hi ? pa : pb;
                const unsigned sw = (unsigned)__shfl_xor((int)pre, 32, 64);
                fu[g][j]     = hi ? sw : pa;
                fu[g][j + 2] = hi ? pb : sw;
            }
        }

        // O += P V
#pragma unroll
        for (int ks = 0; ks < 4; ks++) {
            union { unsigned u[4]; short8 s; } pf;
            pf.u[0] = fu[ks][0]; pf.u[1] = fu[ks][1]; pf.u[2] = fu[ks][2]; pf.u[3] = fu[ks][3];
            const short8 v0 = *(const short8*)&vtl[buf][2*ks + hi][l31][0];
            const short8 v1 = *(const short8*)&vtl[buf][2*ks + hi][32 + l31][0];
            o0 = __builtin_amdgcn_mfma_f32_32x32x16_bf16(pf.s, v0, o0, 0, 0, 0);
            o1 = __builtin_amdgcn_mfma_f32_32x32x16_bf16(pf.s, v1, o1, 0, 0, 0);
        }
    }
#undef STAGE

    // total row sum: own 16 keys/tile + partner half
    rsum += __shfl_xor(rsum, 32, 64);
    const float inv = 1.0f / rsum;   // lane l holds inv for q-row (l&31)

    // epilogue: O C-layout lane = d, regs = q. Normalize + store bf16.
    const int b = bh >> 4, h = bh & 15;
#pragma unroll
    for (int r = 0; r < 16; r++) {
        const int qr = (r & 3) + 8 * (r >> 2) + (hi ? 4 : 0);
        const float invr = __shfl(inv, qr, 64);
        const int seq = q0 + wave*32 + qr;
        short* dst = Ob + ((size_t)(b * SEQ + seq)) * D_MODEL + h * HDIM + l31;
        dst[0]  = f2bf(o0[r] * invr);
        dst[32] = f2bf(o1[r] * invr);
    }
}

// ---------------------------------------------------------------- launch
extern "C" void kernel_launch(void* const* d_in, const int* in_sizes, int n_in,
                              void* d_out, int out_size, void* d_ws, size_t ws_size,
                              hipStream_t stream)
{
    const float* x  = (const float*)d_in[0];
    const float* Wq = (const float*)d_in[1];
    const float* bq = (const float*)d_in[2];
    const float* Wk = (const float*)d_in[3];
    const float* bk = (const float*)d_in[4];
    const float* Wv = (const float*)d_in[5];
    const float* bv = (const float*)d_in[6];
    const float* Wo = (const float*)d_in[7];
    const float* bo = (const float*)d_in[8];
    float* out = (float*)d_out;

    short* ws = (short*)d_ws;
    const size_t NX = (size_t)MTOT * D_MODEL;     // 4194304
    const size_t NW = (size_t)D_MODEL * D_MODEL;  // 1048576
    short* xb  = ws;
    short* wqb = xb  + NX;
    short* wkb = wqb + NW;
    short* wvb = wkb + NW;
    short* wob = wvb + NW;
    short* Qb  = wob + NW;
    short* Kb  = Qb  + NX;
    short* Vb  = Kb  + NX;
    short* Vt  = Vb  + NX;
    short* Ob  = Vt  + NX;

    cast_all_kernel<<<dim3(4096), 256, 0, stream>>>(x, Wq, Wk, Wv, Wo, xb, wqb, wkb, wvb, wob);
    qkv_gemm_kernel<<<dim3(8, 32, 3), 256, 0, stream>>>(xb, wqb, wkb, wvb, bq, bk, bv, Qb, Kb, Vb);
    transpose_v_kernel<<<dim3(32, 32), 256, 0, stream>>>(Vb, Vt);
    attn_kernel<<<dim3(16, 32), 256, 0, stream>>>(Qb, Kb, Vt, Ob);
    out_gemm_kernel<<<dim3(8, 32), 256, 0, stream>>>(Ob, wob, bo, out);
}

// Round 5
// 246.861 us; speedup vs baseline: 1.2842x; 1.0961x over previous
//
#include <hip/hip_runtime.h>
#include <cstdint>
#include <math.h>

typedef __attribute__((ext_vector_type(8))) short short8;
typedef __attribute__((ext_vector_type(4))) short shortx4;
typedef __attribute__((ext_vector_type(4))) float floatx4;
typedef __attribute__((ext_vector_type(16))) float floatx16;

#define D_MODEL 1024
#define NHEAD   16
#define HDIM    64
#define BATCH   2
#define SEQ     2048
#define MTOT    (BATCH*SEQ)   /* 4096 */

#if __has_builtin(__builtin_amdgcn_exp2f)
#define EXP2(x) __builtin_amdgcn_exp2f(x)
#else
#define EXP2(x) exp2f(x)
#endif

// round-to-nearest-even f32 -> bf16 (bits in a short)
__device__ __forceinline__ short f2bf(float f) {
    union { float f; uint32_t u; } v; v.f = f;
    uint32_t u = v.u;
    uint32_t r = (u + 0x7fffu + ((u >> 16) & 1u)) >> 16;
    return (short)(uint16_t)r;
}

// pack two f32 -> [bf16(lo) | bf16(hi)<<16], round-half-up (1-add-each + v_perm)
__device__ __forceinline__ unsigned pk2(float lo, float hi) {
    union { float f; uint32_t u; } x, y; x.f = lo; y.f = hi;
    return __builtin_amdgcn_perm(y.u + 0x8000u, x.u + 0x8000u, 0x07060302u);
}

// async global->LDS, 16B per lane. LDS dest must be wave-uniform base + lane*16.
__device__ __forceinline__ void async16(const short* g, short* l) {
    __builtin_amdgcn_global_load_lds((__attribute__((address_space(1))) void*)g,
                                     (__attribute__((address_space(3))) void*)l,
                                     16, 0, 0);
}

// ---------------------------------------------------------------- merged cast
__global__ __launch_bounds__(256) void cast_all_kernel(
    const float* __restrict__ x,  const float* __restrict__ Wq, const float* __restrict__ Wk,
    const float* __restrict__ Wv, const float* __restrict__ Wo,
    short* __restrict__ xb, short* __restrict__ wqb, short* __restrict__ wkb,
    short* __restrict__ wvb, short* __restrict__ wob)
{
    const int i = blockIdx.x * 256 + threadIdx.x;   // 8-elem group index
    const float* src; short* dst; int off;
    if (i < 524288) { src = x; dst = xb; off = i; }
    else {
        const int j = i - 524288;
        const int seg = j >> 17, o = j & 131071;
        src = (seg == 0) ? Wq : (seg == 1) ? Wk : (seg == 2) ? Wv : Wo;
        dst = (seg == 0) ? wqb : (seg == 1) ? wkb : (seg == 2) ? wvb : wob;
        off = o;
    }
    const floatx4* p = (const floatx4*)(src + (size_t)off * 8);
    floatx4 a = p[0], b = p[1];
    short8 r;
    r[0]=f2bf(a[0]); r[1]=f2bf(a[1]); r[2]=f2bf(a[2]); r[3]=f2bf(a[3]);
    r[4]=f2bf(b[0]); r[5]=f2bf(b[1]); r[6]=f2bf(b[2]); r[7]=f2bf(b[3]);
    *(short8*)(dst + (size_t)off * 8) = r;
}

// ---------------------------------------------------------------- QKV GEMM
// mode 0: Q -> (2v-1)*0.125*log2e, layout [bh][seq][d]
// mode 1: K -> 2v-1,               layout [bh][seq][d]
// mode 2: V -> v,                  layout [bh][d][seq]  (transposed directly)
__global__ __launch_bounds__(256) void qkv_gemm_kernel(
    const short* __restrict__ Xb,
    const short* __restrict__ Wqb, const short* __restrict__ Wkb, const short* __restrict__ Wvb,
    const float* __restrict__ bq, const float* __restrict__ bk, const float* __restrict__ bv,
    short* __restrict__ Qo, short* __restrict__ Ko, short* __restrict__ Vo)
{
    const int mode = blockIdx.z;
    const short* W    = (mode == 0) ? Wqb : (mode == 1) ? Wkb : Wvb;
    const float* bias = (mode == 0) ? bq  : (mode == 1) ? bk  : bv;

    const int m_t = blockIdx.y * 128;
    const int n_t = blockIdx.x * 128;
    const int tid = threadIdx.x;
    const int lane = tid & 63, laneM = lane & 15, quad = lane >> 4;
    const int wave = tid >> 6;
    const int wm = (wave >> 1) * 64, wn = (wave & 1) * 64;

    __shared__ short la[4][128][8];
    __shared__ short lb[4][128][8];

    floatx4 acc[4][4];
#pragma unroll
    for (int mb = 0; mb < 4; mb++)
#pragma unroll
        for (int nb = 0; nb < 4; nb++) acc[mb][nb] = (floatx4){0.f,0.f,0.f,0.f};

    for (int k0 = 0; k0 < D_MODEL; k0 += 32) {
        __syncthreads();
        {
            int c = tid;
            async16(Xb + (size_t)(m_t + (c & 127)) * D_MODEL + k0 + (c >> 7) * 8, &la[0][0][0] + c * 8);
            c = tid + 256;
            async16(Xb + (size_t)(m_t + (c & 127)) * D_MODEL + k0 + (c >> 7) * 8, &la[0][0][0] + c * 8);
            c = tid;
            async16(W  + (size_t)(n_t + (c & 127)) * D_MODEL + k0 + (c >> 7) * 8, &lb[0][0][0] + c * 8);
            c = tid + 256;
            async16(W  + (size_t)(n_t + (c & 127)) * D_MODEL + k0 + (c >> 7) * 8, &lb[0][0][0] + c * 8);
        }
        __syncthreads();

        short8 af[4], bf[4];
#pragma unroll
        for (int mb = 0; mb < 4; mb++) af[mb] = *(const short8*)&la[quad][wm + mb*16 + laneM][0];
#pragma unroll
        for (int nb = 0; nb < 4; nb++) bf[nb] = *(const short8*)&lb[quad][wn + nb*16 + laneM][0];
#pragma unroll
        for (int mb = 0; mb < 4; mb++)
#pragma unroll
            for (int nb = 0; nb < 4; nb++)
                acc[mb][nb] = __builtin_amdgcn_mfma_f32_16x16x32_bf16(af[mb], bf[nb], acc[mb][nb], 0, 0, 0);
    }

    if (mode == 2) {
        // V: store transposed [bh][d][seq], shortx4 along seq
#pragma unroll
        for (int nb = 0; nb < 4; nb++) {
            const int col = n_t + wn + nb*16 + laneM;
            const float bb = bias[col];
            const int h = col >> 6, d = col & 63;
#pragma unroll
            for (int mb = 0; mb < 4; mb++) {
                const int row0 = m_t + wm + mb*16 + quad*4;
                const int bi = row0 >> 11, seq0 = row0 & 2047;
                shortx4 sv;
#pragma unroll
                for (int r = 0; r < 4; r++) sv[r] = f2bf(acc[mb][nb][r] + bb);
                *(shortx4*)(Vo + ((size_t)(bi*NHEAD + h) * HDIM + d) * SEQ + seq0) = sv;
            }
        }
    } else {
        short* out = (mode == 0) ? Qo : Ko;
#pragma unroll
        for (int nb = 0; nb < 4; nb++) {
            const int col = n_t + wn + nb*16 + laneM;
            const float bb = bias[col];
            const int h = col >> 6, d = col & 63;
#pragma unroll
            for (int mb = 0; mb < 4; mb++) {
                const int row0 = m_t + wm + mb*16 + quad*4;
#pragma unroll
                for (int r = 0; r < 4; r++) {
                    float v = acc[mb][nb][r] + bb;
                    v = (mode == 0) ? (2.0f*v - 1.0f) * 0.18033688011112042f  // 0.125*log2(e)
                                    : (2.0f*v - 1.0f);
                    const int m = row0 + r;
                    const int bi = m >> 11, seq = m & 2047;
                    out[((size_t)(bi*NHEAD + h) * SEQ + seq) * HDIM + d] = f2bf(v);
                }
            }
        }
    }
}

// ---------------------------------------------------------------- output GEMM
__global__ __launch_bounds__(256) void out_gemm_kernel(
    const short* __restrict__ Ab, const short* __restrict__ Wb,
    const float* __restrict__ bias, float* __restrict__ out)
{
    const int m_t = blockIdx.y * 128;
    const int n_t = blockIdx.x * 128;
    const int tid = threadIdx.x;
    const int lane = tid & 63, laneM = lane & 15, quad = lane >> 4;
    const int wave = tid >> 6;
    const int wm = (wave >> 1) * 64, wn = (wave & 1) * 64;

    __shared__ short la[4][128][8];
    __shared__ short lb[4][128][8];

    floatx4 acc[4][4];
#pragma unroll
    for (int mb = 0; mb < 4; mb++)
#pragma unroll
        for (int nb = 0; nb < 4; nb++) acc[mb][nb] = (floatx4){0.f,0.f,0.f,0.f};

    for (int k0 = 0; k0 < D_MODEL; k0 += 32) {
        __syncthreads();
        {
            int c = tid;
            async16(Ab + (size_t)(m_t + (c & 127)) * D_MODEL + k0 + (c >> 7) * 8, &la[0][0][0] + c * 8);
            c = tid + 256;
            async16(Ab + (size_t)(m_t + (c & 127)) * D_MODEL + k0 + (c >> 7) * 8, &la[0][0][0] + c * 8);
            c = tid;
            async16(Wb + (size_t)(n_t + (c & 127)) * D_MODEL + k0 + (c >> 7) * 8, &lb[0][0][0] + c * 8);
            c = tid + 256;
            async16(Wb + (size_t)(n_t + (c & 127)) * D_MODEL + k0 + (c >> 7) * 8, &lb[0][0][0] + c * 8);
        }
        __syncthreads();

        short8 af[4], bf[4];
#pragma unroll
        for (int mb = 0; mb < 4; mb++) af[mb] = *(const short8*)&la[quad][wm + mb*16 + laneM][0];
#pragma unroll
        for (int nb = 0; nb < 4; nb++) bf[nb] = *(const short8*)&lb[quad][wn + nb*16 + laneM][0];
#pragma unroll
        for (int mb = 0; mb < 4; mb++)
#pragma unroll
            for (int nb = 0; nb < 4; nb++)
                acc[mb][nb] = __builtin_amdgcn_mfma_f32_16x16x32_bf16(af[mb], bf[nb], acc[mb][nb], 0, 0, 0);
    }

#pragma unroll
    for (int nb = 0; nb < 4; nb++) {
        const int col = n_t + wn + nb*16 + laneM;
        const float bb = bias[col];
#pragma unroll
        for (int mb = 0; mb < 4; mb++) {
            const int row0 = m_t + wm + mb*16 + quad*4;
#pragma unroll
            for (int r = 0; r < 4; r++)
                out[(size_t)(row0 + r) * D_MODEL + col] = acc[mb][nb][r] + bb;
        }
    }
}

// ---------------------------------------------------------------- flash attention
// 8 waves: qg = wave&3 picks 32 q-rows, par = wave>>2 picks key-parity
// (wave computes tiles 2i+par, i=0..15). S computed transposed (A=K, B=Q),
// softmax per-lane (no max needed: s in [-31,54], 2^s fp32/bf16-safe, the
// normalization cancels any offset). P A-frags built in-register
// (pk2 pairs + shfl_xor(32) + cndmask). 4 LDS tile buffers [par][slot],
// prefetched one phase ahead. Parity partials are pure sums -> merged via
// LDS (staging buffers reused) at the end.
__global__ __launch_bounds__(512, 4) void attn_kernel(const short* __restrict__ Qb,
                                                      const short* __restrict__ Kb,
                                                      const short* __restrict__ Vt,
                                                      short* __restrict__ Ob)
{
    const int bh = blockIdx.y;
    const int q0 = blockIdx.x * 128;
    const int tid = threadIdx.x;
    const int wave = tid >> 6, lane = tid & 63;
    const int l31 = lane & 31;
    const bool hi = (lane >> 5) != 0;
    const int qg = wave & 3, par = wave >> 2;

    __shared__ short kt[2][2][8][64][8];    // [par][slot][d-octet][key][8]
    __shared__ short vtl[2][2][8][64][8];   // [par][slot][key-octet][d][8]

    const short* Kbase = Kb + (size_t)bh * SEQ * HDIM;
    const short* Vbase = Vt + (size_t)bh * HDIM * SEQ;

    // Q fragments (MFMA B operand: B[k=d][n=q], lane n = q)
    const short* Qp = Qb + ((size_t)bh * SEQ + q0 + qg*32 + l31) * HDIM + (hi ? 8 : 0);
    short8 qf[4];
#pragma unroll
    for (int ks = 0; ks < 4; ks++) qf[ks] = *(const short8*)(Qp + ks*16);

    floatx16 o0, o1;
#pragma unroll
    for (int r = 0; r < 16; r++) { o0[r] = 0.f; o1[r] = 0.f; }
    float rsum = 0.f;

    // stage key-blocks [kk,kk+64) -> [0][slot] and [kk+64,kk+128) -> [1][slot]
#define STAGE(slot, kk)                                                                   \
    {                                                                                     \
        const int c = tid;                                                                \
        async16(Kbase + (size_t)((kk) + (c & 63)) * HDIM + (c >> 6) * 8,                  \
                &kt[0][slot][0][0][0] + c * 8);                                           \
        async16(Kbase + (size_t)((kk) + 64 + (c & 63)) * HDIM + (c >> 6) * 8,             \
                &kt[1][slot][0][0][0] + c * 8);                                           \
        async16(Vbase + (size_t)(c & 63) * SEQ + (kk) + (c >> 6) * 8,                     \
                &vtl[0][slot][0][0][0] + c * 8);                                          \
        async16(Vbase + (size_t)(c & 63) * SEQ + (kk) + 64 + (c >> 6) * 8,                \
                &vtl[1][slot][0][0][0] + c * 8);                                          \
    }

    STAGE(0, 0)

    for (int i = 0; i < 16; ++i) {
        const int slot = i & 1;
        __syncthreads();                        // both parity tiles of phase i ready
        if (i < 15) STAGE(slot ^ 1, (i + 1) * 128)

        // S^T: D[m=key][n=q]
        floatx16 s0, s1;
#pragma unroll
        for (int r = 0; r < 16; r++) { s0[r] = 0.f; s1[r] = 0.f; }
#pragma unroll
        for (int ks = 0; ks < 4; ks++) {
            const short8 a0 = *(const short8*)&kt[par][slot][2*ks + hi][l31][0];
            const short8 a1 = *(const short8*)&kt[par][slot][2*ks + hi][32 + l31][0];
            s0 = __builtin_amdgcn_mfma_f32_32x32x16_bf16(a0, qf[ks], s0, 0, 0, 0);
            s1 = __builtin_amdgcn_mfma_f32_32x32x16_bf16(a1, qf[ks], s1, 0, 0, 0);
        }

        // p = 2^s (raw v_exp_f32), per-lane rsum, pack adjacent-k pairs
        unsigned p[16];
#pragma unroll
        for (int i2 = 0; i2 < 8; i2++) {
            const float a0 = EXP2(s0[2*i2]), b0 = EXP2(s0[2*i2+1]);
            const float a1 = EXP2(s1[2*i2]), b1 = EXP2(s1[2*i2+1]);
            rsum += (a0 + b0) + (a1 + b1);
            p[i2]     = pk2(a0, b0);
            p[8 + i2] = pk2(a1, b1);
        }

        // build A-fragments: one shuffle serves both slots of a (pa,pb) pair
        unsigned fu[4][4];
#pragma unroll
        for (int g = 0; g < 4; g++) {
            const int base = (g >> 1) * 8 + (g & 1) * 4;  // 0,4,8,12
#pragma unroll
            for (int j = 0; j < 2; j++) {
                const unsigned pa = p[base + j], pb = p[base + j + 2];
                const unsigned pre = hi ? pa : pb;
                const unsigned sw = (unsigned)__shfl_xor((int)pre, 32, 64);
                fu[g][j]     = hi ? sw : pa;
                fu[g][j + 2] = hi ? pb : sw;
            }
        }

        // O += P V
#pragma unroll
        for (int ks = 0; ks < 4; ks++) {
            union { unsigned u[4]; short8 s; } pf;
            pf.u[0] = fu[ks][0]; pf.u[1] = fu[ks][1]; pf.u[2] = fu[ks][2]; pf.u[3] = fu[ks][3];
            const short8 v0 = *(const short8*)&vtl[par][slot][2*ks + hi][l31][0];
            const short8 v1 = *(const short8*)&vtl[par][slot][2*ks + hi][32 + l31][0];
            o0 = __builtin_amdgcn_mfma_f32_32x32x16_bf16(pf.s, v0, o0, 0, 0, 0);
            o1 = __builtin_amdgcn_mfma_f32_32x32x16_bf16(pf.s, v1, o1, 0, 0, 0);
        }
    }
#undef STAGE

    // own-wave key-half combine
    rsum += __shfl_xor(rsum, 32, 64);

    // parity merge via LDS (reuse staging buffers; all compute done after barrier)
    float* mO = (float*)&kt[0][0][0][0][0];     // [4][32][64]
    float* rS = (float*)&vtl[0][0][0][0][0];    // [4][32]
    __syncthreads();
    if (par == 1) {
#pragma unroll
        for (int r = 0; r < 16; r++) {
            const int qr = (r & 3) + 8 * (r >> 2) + (hi ? 4 : 0);
            mO[(qg*32 + qr)*64 + l31]      = o0[r];
            mO[(qg*32 + qr)*64 + 32 + l31] = o1[r];
        }
        if (!hi) rS[qg*32 + l31] = rsum;
    }
    __syncthreads();
    if (par == 0) {
        const float inv = 1.0f / (rsum + rS[qg*32 + l31]);  // lane l: q-row l31
        const int b = bh >> 4, h = bh & 15;
#pragma unroll
        for (int r = 0; r < 16; r++) {
            const int qr = (r & 3) + 8 * (r >> 2) + (hi ? 4 : 0);
            const float invr = __shfl(inv, qr, 64);
            const float v0 = o0[r] + mO[(qg*32 + qr)*64 + l31];
            const float v1 = o1[r] + mO[(qg*32 + qr)*64 + 32 + l31];
            const int seq = q0 + qg*32 + qr;
            short* dst = Ob + ((size_t)(b * SEQ + seq)) * D_MODEL + h * HDIM + l31;
            dst[0]  = f2bf(v0 * invr);
            dst[32] = f2bf(v1 * invr);
        }
    }
}

// ---------------------------------------------------------------- launch
extern "C" void kernel_launch(void* const* d_in, const int* in_sizes, int n_in,
                              void* d_out, int out_size, void* d_ws, size_t ws_size,
                              hipStream_t stream)
{
    const float* x  = (const float*)d_in[0];
    const float* Wq = (const float*)d_in[1];
    const float* bq = (const float*)d_in[2];
    const float* Wk = (const float*)d_in[3];
    const float* bk = (const float*)d_in[4];
    const float* Wv = (const float*)d_in[5];
    const float* bv = (const float*)d_in[6];
    const float* Wo = (const float*)d_in[7];
    const float* bo = (const float*)d_in[8];
    float* out = (float*)d_out;

    short* ws = (short*)d_ws;
    const size_t NX = (size_t)MTOT * D_MODEL;     // 4194304
    const size_t NW = (size_t)D_MODEL * D_MODEL;  // 1048576
    short* xb  = ws;
    short* wqb = xb  + NX;
    short* wkb = wqb + NW;
    short* wvb = wkb + NW;
    short* wob = wvb + NW;
    short* Qb  = wob + NW;
    short* Kb  = Qb  + NX;
    short* Vt  = Kb  + NX;   // V stored transposed directly by qkv_gemm
    short* Ob  = Vt  + NX;

    cast_all_kernel<<<dim3(4096), 256, 0, stream>>>(x, Wq, Wk, Wv, Wo, xb, wqb, wkb, wvb, wob);
    qkv_gemm_kernel<<<dim3(8, 32, 3), 256, 0, stream>>>(xb, wqb, wkb, wvb, bq, bk, bv, Qb, Kb, Vt);
    attn_kernel<<<dim3(16, 32), 512, 0, stream>>>(Qb, Kb, Vt, Ob);
    out_gemm_kernel<<<dim3(8, 32), 256, 0, stream>>>(Ob, wob, bo, out);
}

// Round 6
// 227.738 us; speedup vs baseline: 1.3921x; 1.0840x over previous
//
#include <hip/hip_runtime.h>
#include <cstdint>
#include <math.h>

typedef __attribute__((ext_vector_type(8))) short short8;
typedef __attribute__((ext_vector_type(4))) short shortx4;
typedef __attribute__((ext_vector_type(4))) float floatx4;
typedef __attribute__((ext_vector_type(16))) float floatx16;

#define D_MODEL 1024
#define NHEAD   16
#define HDIM    64
#define BATCH   2
#define SEQ     2048
#define MTOT    (BATCH*SEQ)   /* 4096 */

#if __has_builtin(__builtin_amdgcn_exp2f)
#define EXP2(x) __builtin_amdgcn_exp2f(x)
#else
#define EXP2(x) exp2f(x)
#endif

// round-to-nearest-even f32 -> bf16 (bits in a short)
__device__ __forceinline__ short f2bf(float f) {
    union { float f; uint32_t u; } v; v.f = f;
    uint32_t u = v.u;
    uint32_t r = (u + 0x7fffu + ((u >> 16) & 1u)) >> 16;
    return (short)(uint16_t)r;
}

// pack two f32 -> [bf16(lo) | bf16(hi)<<16], round-half-up (1-add-each + v_perm)
__device__ __forceinline__ unsigned pk2(float lo, float hi) {
    union { float f; uint32_t u; } x, y; x.f = lo; y.f = hi;
    return __builtin_amdgcn_perm(y.u + 0x8000u, x.u + 0x8000u, 0x07060302u);
}

// async global->LDS, 16B per lane. LDS dest must be wave-uniform base + lane*16.
__device__ __forceinline__ void async16(const short* g, short* l) {
    __builtin_amdgcn_global_load_lds((__attribute__((address_space(1))) void*)g,
                                     (__attribute__((address_space(3))) void*)l,
                                     16, 0, 0);
}

// ---------------------------------------------------------------- merged cast
__global__ __launch_bounds__(256) void cast_all_kernel(
    const float* __restrict__ x,  const float* __restrict__ Wq, const float* __restrict__ Wk,
    const float* __restrict__ Wv, const float* __restrict__ Wo,
    short* __restrict__ xb, short* __restrict__ wqb, short* __restrict__ wkb,
    short* __restrict__ wvb, short* __restrict__ wob)
{
    const int i = blockIdx.x * 256 + threadIdx.x;   // 8-elem group index
    const float* src; short* dst; int off;
    if (i < 524288) { src = x; dst = xb; off = i; }
    else {
        const int j = i - 524288;
        const int seg = j >> 17, o = j & 131071;
        src = (seg == 0) ? Wq : (seg == 1) ? Wk : (seg == 2) ? Wv : Wo;
        dst = (seg == 0) ? wqb : (seg == 1) ? wkb : (seg == 2) ? wvb : wob;
        off = o;
    }
    const floatx4* p = (const floatx4*)(src + (size_t)off * 8);
    floatx4 a = p[0], b = p[1];
    short8 r;
    r[0]=f2bf(a[0]); r[1]=f2bf(a[1]); r[2]=f2bf(a[2]); r[3]=f2bf(a[3]);
    r[4]=f2bf(b[0]); r[5]=f2bf(b[1]); r[6]=f2bf(b[2]); r[7]=f2bf(b[3]);
    *(short8*)(dst + (size_t)off * 8) = r;
}

// ---------------------------------------------------------------- QKV GEMM
// Double-buffered K-loop + XOR-swizzled LDS tiles:
//   LDS[row][j][8] holds global k-octet j ^ ((row>>2)&3).
//   Store (lane c): row=c>>2, slot=c&3, global octet=(c&3)^((c>>4)&3)
//     -> 4 lanes of a row read one 64B line (coalesced, 16 lines/instr).
//   Read: octet `quad` of row -> slot quad^(laneM>>2); bank groups hit
//     exactly 2-way (free).
// mode 0: Q -> (2v-1)*0.125*log2e, [bh][seq][d]; mode 1: K -> 2v-1, same;
// mode 2: V -> v, [bh][d][seq] (transposed directly).
__global__ __launch_bounds__(256) void qkv_gemm_kernel(
    const short* __restrict__ Xb,
    const short* __restrict__ Wqb, const short* __restrict__ Wkb, const short* __restrict__ Wvb,
    const float* __restrict__ bq, const float* __restrict__ bk, const float* __restrict__ bv,
    short* __restrict__ Qo, short* __restrict__ Ko, short* __restrict__ Vo)
{
    const int mode = blockIdx.z;
    const short* W    = (mode == 0) ? Wqb : (mode == 1) ? Wkb : Wvb;
    const float* bias = (mode == 0) ? bq  : (mode == 1) ? bk  : bv;

    const int m_t = blockIdx.y * 128;
    const int n_t = blockIdx.x * 128;
    const int tid = threadIdx.x;
    const int lane = tid & 63, laneM = lane & 15, quad = lane >> 4;
    const int wave = tid >> 6;
    const int wm = (wave >> 1) * 64, wn = (wave & 1) * 64;

    __shared__ short la[2][128][4][8];   // [buf][row][slot][8]
    __shared__ short lb[2][128][4][8];

    floatx4 acc[4][4];
#pragma unroll
    for (int mb = 0; mb < 4; mb++)
#pragma unroll
        for (int nb = 0; nb < 4; nb++) acc[mb][nb] = (floatx4){0.f,0.f,0.f,0.f};

#define QSTAGE(bf, kk)                                                                  \
    {                                                                                   \
        int c = tid;                                                                    \
        async16(Xb + (size_t)(m_t + (c >> 2)) * D_MODEL + (kk) + (((c & 3) ^ ((c >> 4) & 3)) * 8), \
                &la[bf][0][0][0] + c * 8);                                              \
        c = tid + 256;                                                                  \
        async16(Xb + (size_t)(m_t + (c >> 2)) * D_MODEL + (kk) + (((c & 3) ^ ((c >> 4) & 3)) * 8), \
                &la[bf][0][0][0] + c * 8);                                              \
        c = tid;                                                                        \
        async16(W  + (size_t)(n_t + (c >> 2)) * D_MODEL + (kk) + (((c & 3) ^ ((c >> 4) & 3)) * 8), \
                &lb[bf][0][0][0] + c * 8);                                              \
        c = tid + 256;                                                                  \
        async16(W  + (size_t)(n_t + (c >> 2)) * D_MODEL + (kk) + (((c & 3) ^ ((c >> 4) & 3)) * 8), \
                &lb[bf][0][0][0] + c * 8);                                              \
    }

    QSTAGE(0, 0)

    for (int it = 0; it < 32; ++it) {
        const int bf = it & 1;
        __syncthreads();                       // buf[it] ready (prefetch had a full compute phase)
        if (it < 31) QSTAGE(bf ^ 1, (it + 1) * 32)

        const int swz = laneM >> 2;
        short8 af[4], bfv[4];
#pragma unroll
        for (int mb = 0; mb < 4; mb++) af[mb]  = *(const short8*)&la[bf][wm + mb*16 + laneM][quad ^ swz][0];
#pragma unroll
        for (int nb = 0; nb < 4; nb++) bfv[nb] = *(const short8*)&lb[bf][wn + nb*16 + laneM][quad ^ swz][0];
#pragma unroll
        for (int mb = 0; mb < 4; mb++)
#pragma unroll
            for (int nb = 0; nb < 4; nb++)
                acc[mb][nb] = __builtin_amdgcn_mfma_f32_16x16x32_bf16(af[mb], bfv[nb], acc[mb][nb], 0, 0, 0);
    }
#undef QSTAGE

    if (mode == 2) {
        // V: store transposed [bh][d][seq], shortx4 along seq
#pragma unroll
        for (int nb = 0; nb < 4; nb++) {
            const int col = n_t + wn + nb*16 + laneM;
            const float bb = bias[col];
            const int h = col >> 6, d = col & 63;
#pragma unroll
            for (int mb = 0; mb < 4; mb++) {
                const int row0 = m_t + wm + mb*16 + quad*4;
                const int bi = row0 >> 11, seq0 = row0 & 2047;
                shortx4 sv;
#pragma unroll
                for (int r = 0; r < 4; r++) sv[r] = f2bf(acc[mb][nb][r] + bb);
                *(shortx4*)(Vo + ((size_t)(bi*NHEAD + h) * HDIM + d) * SEQ + seq0) = sv;
            }
        }
    } else {
        short* out = (mode == 0) ? Qo : Ko;
#pragma unroll
        for (int nb = 0; nb < 4; nb++) {
            const int col = n_t + wn + nb*16 + laneM;
            const float bb = bias[col];
            const int h = col >> 6, d = col & 63;
#pragma unroll
            for (int mb = 0; mb < 4; mb++) {
                const int row0 = m_t + wm + mb*16 + quad*4;
#pragma unroll
                for (int r = 0; r < 4; r++) {
                    float v = acc[mb][nb][r] + bb;
                    v = (mode == 0) ? (2.0f*v - 1.0f) * 0.18033688011112042f  // 0.125*log2(e)
                                    : (2.0f*v - 1.0f);
                    const int m = row0 + r;
                    const int bi = m >> 11, seq = m & 2047;
                    out[((size_t)(bi*NHEAD + h) * SEQ + seq) * HDIM + d] = f2bf(v);
                }
            }
        }
    }
}

// ---------------------------------------------------------------- output GEMM
// Same dbuf + swizzle structure as qkv_gemm.
__global__ __launch_bounds__(256) void out_gemm_kernel(
    const short* __restrict__ Ab, const short* __restrict__ Wb,
    const float* __restrict__ bias, float* __restrict__ out)
{
    const int m_t = blockIdx.y * 128;
    const int n_t = blockIdx.x * 128;
    const int tid = threadIdx.x;
    const int lane = tid & 63, laneM = lane & 15, quad = lane >> 4;
    const int wave = tid >> 6;
    const int wm = (wave >> 1) * 64, wn = (wave & 1) * 64;

    __shared__ short la[2][128][4][8];
    __shared__ short lb[2][128][4][8];

    floatx4 acc[4][4];
#pragma unroll
    for (int mb = 0; mb < 4; mb++)
#pragma unroll
        for (int nb = 0; nb < 4; nb++) acc[mb][nb] = (floatx4){0.f,0.f,0.f,0.f};

#define OSTAGE(bf, kk)                                                                  \
    {                                                                                   \
        int c = tid;                                                                    \
        async16(Ab + (size_t)(m_t + (c >> 2)) * D_MODEL + (kk) + (((c & 3) ^ ((c >> 4) & 3)) * 8), \
                &la[bf][0][0][0] + c * 8);                                              \
        c = tid + 256;                                                                  \
        async16(Ab + (size_t)(m_t + (c >> 2)) * D_MODEL + (kk) + (((c & 3) ^ ((c >> 4) & 3)) * 8), \
                &la[bf][0][0][0] + c * 8);                                              \
        c = tid;                                                                        \
        async16(Wb + (size_t)(n_t + (c >> 2)) * D_MODEL + (kk) + (((c & 3) ^ ((c >> 4) & 3)) * 8), \
                &lb[bf][0][0][0] + c * 8);                                              \
        c = tid + 256;                                                                  \
        async16(Wb + (size_t)(n_t + (c >> 2)) * D_MODEL + (kk) + (((c & 3) ^ ((c >> 4) & 3)) * 8), \
                &lb[bf][0][0][0] + c * 8);                                              \
    }

    OSTAGE(0, 0)

    for (int it = 0; it < 32; ++it) {
        const int bf = it & 1;
        __syncthreads();
        if (it < 31) OSTAGE(bf ^ 1, (it + 1) * 32)

        const int swz = laneM >> 2;
        short8 af[4], bfv[4];
#pragma unroll
        for (int mb = 0; mb < 4; mb++) af[mb]  = *(const short8*)&la[bf][wm + mb*16 + laneM][quad ^ swz][0];
#pragma unroll
        for (int nb = 0; nb < 4; nb++) bfv[nb] = *(const short8*)&lb[bf][wn + nb*16 + laneM][quad ^ swz][0];
#pragma unroll
        for (int mb = 0; mb < 4; mb++)
#pragma unroll
            for (int nb = 0; nb < 4; nb++)
                acc[mb][nb] = __builtin_amdgcn_mfma_f32_16x16x32_bf16(af[mb], bfv[nb], acc[mb][nb], 0, 0, 0);
    }
#undef OSTAGE

#pragma unroll
    for (int nb = 0; nb < 4; nb++) {
        const int col = n_t + wn + nb*16 + laneM;
        const float bb = bias[col];
#pragma unroll
        for (int mb = 0; mb < 4; mb++) {
            const int row0 = m_t + wm + mb*16 + quad*4;
#pragma unroll
            for (int r = 0; r < 4; r++)
                out[(size_t)(row0 + r) * D_MODEL + col] = acc[mb][nb][r] + bb;
        }
    }
}

// ---------------------------------------------------------------- flash attention
// (unchanged from R5 — 8 waves, parity split, dbuf, in-register P frags)
__global__ __launch_bounds__(512, 4) void attn_kernel(const short* __restrict__ Qb,
                                                      const short* __restrict__ Kb,
                                                      const short* __restrict__ Vt,
                                                      short* __restrict__ Ob)
{
    const int bh = blockIdx.y;
    const int q0 = blockIdx.x * 128;
    const int tid = threadIdx.x;
    const int wave = tid >> 6, lane = tid & 63;
    const int l31 = lane & 31;
    const bool hi = (lane >> 5) != 0;
    const int qg = wave & 3, par = wave >> 2;

    __shared__ short kt[2][2][8][64][8];    // [par][slot][d-octet][key][8]
    __shared__ short vtl[2][2][8][64][8];   // [par][slot][key-octet][d][8]

    const short* Kbase = Kb + (size_t)bh * SEQ * HDIM;
    const short* Vbase = Vt + (size_t)bh * HDIM * SEQ;

    // Q fragments (MFMA B operand: B[k=d][n=q], lane n = q)
    const short* Qp = Qb + ((size_t)bh * SEQ + q0 + qg*32 + l31) * HDIM + (hi ? 8 : 0);
    short8 qf[4];
#pragma unroll
    for (int ks = 0; ks < 4; ks++) qf[ks] = *(const short8*)(Qp + ks*16);

    floatx16 o0, o1;
#pragma unroll
    for (int r = 0; r < 16; r++) { o0[r] = 0.f; o1[r] = 0.f; }
    float rsum = 0.f;

#define STAGE(slot, kk)                                                                   \
    {                                                                                     \
        const int c = tid;                                                                \
        async16(Kbase + (size_t)((kk) + (c & 63)) * HDIM + (c >> 6) * 8,                  \
                &kt[0][slot][0][0][0] + c * 8);                                           \
        async16(Kbase + (size_t)((kk) + 64 + (c & 63)) * HDIM + (c >> 6) * 8,             \
                &kt[1][slot][0][0][0] + c * 8);                                           \
        async16(Vbase + (size_t)(c & 63) * SEQ + (kk) + (c >> 6) * 8,                     \
                &vtl[0][slot][0][0][0] + c * 8);                                          \
        async16(Vbase + (size_t)(c & 63) * SEQ + (kk) + 64 + (c >> 6) * 8,                \
                &vtl[1][slot][0][0][0] + c * 8);                                          \
    }

    STAGE(0, 0)

    for (int i = 0; i < 16; ++i) {
        const int slot = i & 1;
        __syncthreads();                        // both parity tiles of phase i ready
        if (i < 15) STAGE(slot ^ 1, (i + 1) * 128)

        // S^T: D[m=key][n=q]
        floatx16 s0, s1;
#pragma unroll
        for (int r = 0; r < 16; r++) { s0[r] = 0.f; s1[r] = 0.f; }
#pragma unroll
        for (int ks = 0; ks < 4; ks++) {
            const short8 a0 = *(const short8*)&kt[par][slot][2*ks + hi][l31][0];
            const short8 a1 = *(const short8*)&kt[par][slot][2*ks + hi][32 + l31][0];
            s0 = __builtin_amdgcn_mfma_f32_32x32x16_bf16(a0, qf[ks], s0, 0, 0, 0);
            s1 = __builtin_amdgcn_mfma_f32_32x32x16_bf16(a1, qf[ks], s1, 0, 0, 0);
        }

        // p = 2^s (raw v_exp_f32), per-lane rsum, pack adjacent-k pairs
        unsigned p[16];
#pragma unroll
        for (int i2 = 0; i2 < 8; i2++) {
            const float a0 = EXP2(s0[2*i2]), b0 = EXP2(s0[2*i2+1]);
            const float a1 = EXP2(s1[2*i2]), b1 = EXP2(s1[2*i2+1]);
            rsum += (a0 + b0) + (a1 + b1);
            p[i2]     = pk2(a0, b0);
            p[8 + i2] = pk2(a1, b1);
        }

        // build A-fragments: one shuffle serves both slots of a (pa,pb) pair
        unsigned fu[4][4];
#pragma unroll
        for (int g = 0; g < 4; g++) {
            const int base = (g >> 1) * 8 + (g & 1) * 4;  // 0,4,8,12
#pragma unroll
            for (int j = 0; j < 2; j++) {
                const unsigned pa = p[base + j], pb = p[base + j + 2];
                const unsigned pre = hi ? pa : pb;
                const unsigned sw = (unsigned)__shfl_xor((int)pre, 32, 64);
                fu[g][j]     = hi ? sw : pa;
                fu[g][j + 2] = hi ? pb : sw;
            }
        }

        // O += P V
#pragma unroll
        for (int ks = 0; ks < 4; ks++) {
            union { unsigned u[4]; short8 s; } pf;
            pf.u[0] = fu[ks][0]; pf.u[1] = fu[ks][1]; pf.u[2] = fu[ks][2]; pf.u[3] = fu[ks][3];
            const short8 v0 = *(const short8*)&vtl[par][slot][2*ks + hi][l31][0];
            const short8 v1 = *(const short8*)&vtl[par][slot][2*ks + hi][32 + l31][0];
            o0 = __builtin_amdgcn_mfma_f32_32x32x16_bf16(pf.s, v0, o0, 0, 0, 0);
            o1 = __builtin_amdgcn_mfma_f32_32x32x16_bf16(pf.s, v1, o1, 0, 0, 0);
        }
    }
#undef STAGE

    // own-wave key-half combine
    rsum += __shfl_xor(rsum, 32, 64);

    // parity merge via LDS (reuse staging buffers; all compute done after barrier)
    float* mO = (float*)&kt[0][0][0][0][0];     // [4][32][64]
    float* rS = (float*)&vtl[0][0][0][0][0];    // [4][32]
    __syncthreads();
    if (par == 1) {
#pragma unroll
        for (int r = 0; r < 16; r++) {
            const int qr = (r & 3) + 8 * (r >> 2) + (hi ? 4 : 0);
            mO[(qg*32 + qr)*64 + l31]      = o0[r];
            mO[(qg*32 + qr)*64 + 32 + l31] = o1[r];
        }
        if (!hi) rS[qg*32 + l31] = rsum;
    }
    __syncthreads();
    if (par == 0) {
        const float inv = 1.0f / (rsum + rS[qg*32 + l31]);  // lane l: q-row l31
        const int b = bh >> 4, h = bh & 15;
#pragma unroll
        for (int r = 0; r < 16; r++) {
            const int qr = (r & 3) + 8 * (r >> 2) + (hi ? 4 : 0);
            const float invr = __shfl(inv, qr, 64);
            const float v0 = o0[r] + mO[(qg*32 + qr)*64 + l31];
            const float v1 = o1[r] + mO[(qg*32 + qr)*64 + 32 + l31];
            const int seq = q0 + qg*32 + qr;
            short* dst = Ob + ((size_t)(b * SEQ + seq)) * D_MODEL + h * HDIM + l31;
            dst[0]  = f2bf(v0 * invr);
            dst[32] = f2bf(v1 * invr);
        }
    }
}

// ---------------------------------------------------------------- launch
extern "C" void kernel_launch(void* const* d_in, const int* in_sizes, int n_in,
                              void* d_out, int out_size, void* d_ws, size_t ws_size,
                              hipStream_t stream)
{
    const float* x  = (const float*)d_in[0];
    const float* Wq = (const float*)d_in[1];
    const float* bq = (const float*)d_in[2];
    const float* Wk = (const float*)d_in[3];
    const float* bk = (const float*)d_in[4];
    const float* Wv = (const float*)d_in[5];
    const float* bv = (const float*)d_in[6];
    const float* Wo = (const float*)d_in[7];
    const float* bo = (const float*)d_in[8];
    float* out = (float*)d_out;

    short* ws = (short*)d_ws;
    const size_t NX = (size_t)MTOT * D_MODEL;     // 4194304
    const size_t NW = (size_t)D_MODEL * D_MODEL;  // 1048576
    short* xb  = ws;
    short* wqb = xb  + NX;
    short* wkb = wqb + NW;
    short* wvb = wkb + NW;
    short* wob = wvb + NW;
    short* Qb  = wob + NW;
    short* Kb  = Qb  + NX;
    short* Vt  = Kb  + NX;   // V stored transposed directly by qkv_gemm
    short* Ob  = Vt  + NX;

    cast_all_kernel<<<dim3(4096), 256, 0, stream>>>(x, Wq, Wk, Wv, Wo, xb, wqb, wkb, wvb, wob);
    qkv_gemm_kernel<<<dim3(8, 32, 3), 256, 0, stream>>>(xb, wqb, wkb, wvb, bq, bk, bv, Qb, Kb, Vt);
    attn_kernel<<<dim3(16, 32), 512, 0, stream>>>(Qb, Kb, Vt, Ob);
    out_gemm_kernel<<<dim3(8, 32), 256, 0, stream>>>(Ob, wob, bo, out);
}

// Round 7
// 191.680 us; speedup vs baseline: 1.6539x; 1.1881x over previous
//
#include <hip/hip_runtime.h>
#include <cstdint>
#include <math.h>

typedef __attribute__((ext_vector_type(8))) short short8;
typedef __attribute__((ext_vector_type(4))) short shortx4;
typedef __attribute__((ext_vector_type(4))) float floatx4;
typedef __attribute__((ext_vector_type(16))) float floatx16;

#define D_MODEL 1024
#define NHEAD   16
#define HDIM    64
#define BATCH   2
#define SEQ     2048
#define MTOT    (BATCH*SEQ)   /* 4096 */

#if __has_builtin(__builtin_amdgcn_exp2f)
#define EXP2(x) __builtin_amdgcn_exp2f(x)
#else
#define EXP2(x) exp2f(x)
#endif

// round-to-nearest-even f32 -> bf16 (bits in a short)
__device__ __forceinline__ short f2bf(float f) {
    union { float f; uint32_t u; } v; v.f = f;
    uint32_t u = v.u;
    uint32_t r = (u + 0x7fffu + ((u >> 16) & 1u)) >> 16;
    return (short)(uint16_t)r;
}

// pack two f32 -> [bf16(lo) | bf16(hi)<<16], round-half-up (1-add-each + v_perm)
__device__ __forceinline__ unsigned pk2(float lo, float hi) {
    union { float f; uint32_t u; } x, y; x.f = lo; y.f = hi;
    return __builtin_amdgcn_perm(y.u + 0x8000u, x.u + 0x8000u, 0x07060302u);
}

// async global->LDS, 16B per lane. LDS dest must be wave-uniform base + lane*16.
__device__ __forceinline__ void async16(const short* g, short* l) {
    __builtin_amdgcn_global_load_lds((__attribute__((address_space(1))) void*)g,
                                     (__attribute__((address_space(3))) void*)l,
                                     16, 0, 0);
}

// ---------------------------------------------------------------- merged cast
__global__ __launch_bounds__(256) void cast_all_kernel(
    const float* __restrict__ x,  const float* __restrict__ Wq, const float* __restrict__ Wk,
    const float* __restrict__ Wv, const float* __restrict__ Wo,
    short* __restrict__ xb, short* __restrict__ wqb, short* __restrict__ wkb,
    short* __restrict__ wvb, short* __restrict__ wob)
{
    const int i = blockIdx.x * 256 + threadIdx.x;   // 8-elem group index
    const float* src; short* dst; int off;
    if (i < 524288) { src = x; dst = xb; off = i; }
    else {
        const int j = i - 524288;
        const int seg = j >> 17, o = j & 131071;
        src = (seg == 0) ? Wq : (seg == 1) ? Wk : (seg == 2) ? Wv : Wo;
        dst = (seg == 0) ? wqb : (seg == 1) ? wkb : (seg == 2) ? wvb : wob;
        off = o;
    }
    const floatx4* p = (const floatx4*)(src + (size_t)off * 8);
    floatx4 a = p[0], b = p[1];
    short8 r;
    r[0]=f2bf(a[0]); r[1]=f2bf(a[1]); r[2]=f2bf(a[2]); r[3]=f2bf(a[3]);
    r[4]=f2bf(b[0]); r[5]=f2bf(b[1]); r[6]=f2bf(b[2]); r[7]=f2bf(b[3]);
    *(short8*)(dst + (size_t)off * 8) = r;
}

// ---------------------------------------------------------------- QKV GEMM
// Swizzled LDS: chunk c (16B) = (row = c>>2, slot = c&3); slot holds global
// k-octet slot ^ ((row>>1)&3).
//   Store (lane c): 4 consecutive lanes cover one 64B line -> coalesced.
//   Read (row R, octet q) at slot q^((R>>1)&3): within each 8-lane DS batch,
//   bank group = 16*(laneM&1) + 4*(quad^((laneM>>1)&3)) -> all distinct,
//   conflict-free.
// Per iteration: barrier -> ds_read frags -> prefetch(buf^1) -> MFMA, so the
// barrier drain is covered by MFMA and reads can't be delayed by vmem alias.
// mode 0: Q -> (2v-1)*0.125*log2e, [bh][seq][d]; mode 1: K -> 2v-1, same;
// mode 2: V -> v, [bh][d][seq] (transposed directly).
__global__ __launch_bounds__(256, 3) void qkv_gemm_kernel(
    const short* __restrict__ Xb,
    const short* __restrict__ Wqb, const short* __restrict__ Wkb, const short* __restrict__ Wvb,
    const float* __restrict__ bq, const float* __restrict__ bk, const float* __restrict__ bv,
    short* __restrict__ Qo, short* __restrict__ Ko, short* __restrict__ Vo)
{
    const int mode = blockIdx.z;
    const short* W    = (mode == 0) ? Wqb : (mode == 1) ? Wkb : Wvb;
    const float* bias = (mode == 0) ? bq  : (mode == 1) ? bk  : bv;

    const int m_t = blockIdx.y * 128;
    const int n_t = blockIdx.x * 128;
    const int tid = threadIdx.x;
    const int lane = tid & 63, laneM = lane & 15, quad = lane >> 4;
    const int wave = tid >> 6;
    const int wm = (wave >> 1) * 64, wn = (wave & 1) * 64;

    __shared__ short la[2][128][4][8];   // [buf][row][slot][8]
    __shared__ short lb[2][128][4][8];

    floatx4 acc[4][4];
#pragma unroll
    for (int mb = 0; mb < 4; mb++)
#pragma unroll
        for (int nb = 0; nb < 4; nb++) acc[mb][nb] = (floatx4){0.f,0.f,0.f,0.f};

    // lane c stages (row=c>>2, global octet=(c&3)^((c>>3)&3))
#define QSTAGE(bf, kk)                                                                  \
    {                                                                                   \
        int c = tid;                                                                    \
        async16(Xb + (size_t)(m_t + (c >> 2)) * D_MODEL + (kk) + ((((c & 3) ^ ((c >> 3) & 3))) * 8), \
                &la[bf][0][0][0] + c * 8);                                              \
        c = tid + 256;                                                                  \
        async16(Xb + (size_t)(m_t + (c >> 2)) * D_MODEL + (kk) + ((((c & 3) ^ ((c >> 3) & 3))) * 8), \
                &la[bf][0][0][0] + c * 8);                                              \
        c = tid;                                                                        \
        async16(W  + (size_t)(n_t + (c >> 2)) * D_MODEL + (kk) + ((((c & 3) ^ ((c >> 3) & 3))) * 8), \
                &lb[bf][0][0][0] + c * 8);                                              \
        c = tid + 256;                                                                  \
        async16(W  + (size_t)(n_t + (c >> 2)) * D_MODEL + (kk) + ((((c & 3) ^ ((c >> 3) & 3))) * 8), \
                &lb[bf][0][0][0] + c * 8);                                              \
    }

    QSTAGE(0, 0)

    const int swz = (laneM >> 1) & 3;
    for (int it = 0; it < 32; ++it) {
        const int bf = it & 1;
        __syncthreads();                       // buf[it] ready

        short8 af[4], bfv[4];
#pragma unroll
        for (int mb = 0; mb < 4; mb++) af[mb]  = *(const short8*)&la[bf][wm + mb*16 + laneM][quad ^ swz][0];
#pragma unroll
        for (int nb = 0; nb < 4; nb++) bfv[nb] = *(const short8*)&lb[bf][wn + nb*16 + laneM][quad ^ swz][0];

        if (it < 31) QSTAGE(bf ^ 1, (it + 1) * 32)

#pragma unroll
        for (int mb = 0; mb < 4; mb++)
#pragma unroll
            for (int nb = 0; nb < 4; nb++)
                acc[mb][nb] = __builtin_amdgcn_mfma_f32_16x16x32_bf16(af[mb], bfv[nb], acc[mb][nb], 0, 0, 0);
    }
#undef QSTAGE

    if (mode == 2) {
        // V: store transposed [bh][d][seq], shortx4 along seq
#pragma unroll
        for (int nb = 0; nb < 4; nb++) {
            const int col = n_t + wn + nb*16 + laneM;
            const float bb = bias[col];
            const int h = col >> 6, d = col & 63;
#pragma unroll
            for (int mb = 0; mb < 4; mb++) {
                const int row0 = m_t + wm + mb*16 + quad*4;
                const int bi = row0 >> 11, seq0 = row0 & 2047;
                shortx4 sv;
#pragma unroll
                for (int r = 0; r < 4; r++) sv[r] = f2bf(acc[mb][nb][r] + bb);
                *(shortx4*)(Vo + ((size_t)(bi*NHEAD + h) * HDIM + d) * SEQ + seq0) = sv;
            }
        }
    } else {
        short* out = (mode == 0) ? Qo : Ko;
#pragma unroll
        for (int nb = 0; nb < 4; nb++) {
            const int col = n_t + wn + nb*16 + laneM;
            const float bb = bias[col];
            const int h = col >> 6, d = col & 63;
#pragma unroll
            for (int mb = 0; mb < 4; mb++) {
                const int row0 = m_t + wm + mb*16 + quad*4;
#pragma unroll
                for (int r = 0; r < 4; r++) {
                    float v = acc[mb][nb][r] + bb;
                    v = (mode == 0) ? (2.0f*v - 1.0f) * 0.18033688011112042f  // 0.125*log2(e)
                                    : (2.0f*v - 1.0f);
                    const int m = row0 + r;
                    const int bi = m >> 11, seq = m & 2047;
                    out[((size_t)(bi*NHEAD + h) * SEQ + seq) * HDIM + d] = f2bf(v);
                }
            }
        }
    }
}

// ---------------------------------------------------------------- output GEMM
// 128x64 tile, grid(16,32)=512 blocks -> 2 blocks/CU. 4 waves, each 64x32
// (4x2 MFMA blocks). Same swizzle + read-then-prefetch structure.
__global__ __launch_bounds__(256, 3) void out_gemm_kernel(
    const short* __restrict__ Ab, const short* __restrict__ Wb,
    const float* __restrict__ bias, float* __restrict__ out)
{
    const int m_t = blockIdx.y * 128;
    const int n_t = blockIdx.x * 64;
    const int tid = threadIdx.x;
    const int lane = tid & 63, laneM = lane & 15, quad = lane >> 4;
    const int wave = tid >> 6;
    const int wm = (wave >> 1) * 64, wn = (wave & 1) * 32;

    __shared__ short la[2][128][4][8];   // 8 KB per buf
    __shared__ short lb[2][64][4][8];    // 4 KB per buf

    floatx4 acc[4][2];
#pragma unroll
    for (int mb = 0; mb < 4; mb++)
#pragma unroll
        for (int nb = 0; nb < 2; nb++) acc[mb][nb] = (floatx4){0.f,0.f,0.f,0.f};

#define OSTAGE(bf, kk)                                                                  \
    {                                                                                   \
        int c = tid;                                                                    \
        async16(Ab + (size_t)(m_t + (c >> 2)) * D_MODEL + (kk) + ((((c & 3) ^ ((c >> 3) & 3))) * 8), \
                &la[bf][0][0][0] + c * 8);                                              \
        c = tid + 256;                                                                  \
        async16(Ab + (size_t)(m_t + (c >> 2)) * D_MODEL + (kk) + ((((c & 3) ^ ((c >> 3) & 3))) * 8), \
                &la[bf][0][0][0] + c * 8);                                              \
        c = tid;                                                                        \
        async16(Wb + (size_t)(n_t + (c >> 2)) * D_MODEL + (kk) + ((((c & 3) ^ ((c >> 3) & 3))) * 8), \
                &lb[bf][0][0][0] + c * 8);                                              \
    }

    OSTAGE(0, 0)

    const int swz = (laneM >> 1) & 3;
    for (int it = 0; it < 32; ++it) {
        const int bf = it & 1;
        __syncthreads();

        short8 af[4], bfv[2];
#pragma unroll
        for (int mb = 0; mb < 4; mb++) af[mb]  = *(const short8*)&la[bf][wm + mb*16 + laneM][quad ^ swz][0];
#pragma unroll
        for (int nb = 0; nb < 2; nb++) bfv[nb] = *(const short8*)&lb[bf][wn + nb*16 + laneM][quad ^ swz][0];

        if (it < 31) OSTAGE(bf ^ 1, (it + 1) * 32)

#pragma unroll
        for (int mb = 0; mb < 4; mb++)
#pragma unroll
            for (int nb = 0; nb < 2; nb++)
                acc[mb][nb] = __builtin_amdgcn_mfma_f32_16x16x32_bf16(af[mb], bfv[nb], acc[mb][nb], 0, 0, 0);
    }
#undef OSTAGE

#pragma unroll
    for (int nb = 0; nb < 2; nb++) {
        const int col = n_t + wn + nb*16 + laneM;
        const float bb = bias[col];
#pragma unroll
        for (int mb = 0; mb < 4; mb++) {
            const int row0 = m_t + wm + mb*16 + quad*4;
#pragma unroll
            for (int r = 0; r < 4; r++)
                out[(size_t)(row0 + r) * D_MODEL + col] = acc[mb][nb][r] + bb;
        }
    }
}

// ---------------------------------------------------------------- flash attention
// (unchanged from R6 — 8 waves, parity split, dbuf, in-register P frags)
__global__ __launch_bounds__(512, 4) void attn_kernel(const short* __restrict__ Qb,
                                                      const short* __restrict__ Kb,
                                                      const short* __restrict__ Vt,
                                                      short* __restrict__ Ob)
{
    const int bh = blockIdx.y;
    const int q0 = blockIdx.x * 128;
    const int tid = threadIdx.x;
    const int wave = tid >> 6, lane = tid & 63;
    const int l31 = lane & 31;
    const bool hi = (lane >> 5) != 0;
    const int qg = wave & 3, par = wave >> 2;

    __shared__ short kt[2][2][8][64][8];    // [par][slot][d-octet][key][8]
    __shared__ short vtl[2][2][8][64][8];   // [par][slot][key-octet][d][8]

    const short* Kbase = Kb + (size_t)bh * SEQ * HDIM;
    const short* Vbase = Vt + (size_t)bh * HDIM * SEQ;

    // Q fragments (MFMA B operand: B[k=d][n=q], lane n = q)
    const short* Qp = Qb + ((size_t)bh * SEQ + q0 + qg*32 + l31) * HDIM + (hi ? 8 : 0);
    short8 qf[4];
#pragma unroll
    for (int ks = 0; ks < 4; ks++) qf[ks] = *(const short8*)(Qp + ks*16);

    floatx16 o0, o1;
#pragma unroll
    for (int r = 0; r < 16; r++) { o0[r] = 0.f; o1[r] = 0.f; }
    float rsum = 0.f;

#define STAGE(slot, kk)                                                                   \
    {                                                                                     \
        const int c = tid;                                                                \
        async16(Kbase + (size_t)((kk) + (c & 63)) * HDIM + (c >> 6) * 8,                  \
                &kt[0][slot][0][0][0] + c * 8);                                           \
        async16(Kbase + (size_t)((kk) + 64 + (c & 63)) * HDIM + (c >> 6) * 8,             \
                &kt[1][slot][0][0][0] + c * 8);                                           \
        async16(Vbase + (size_t)(c & 63) * SEQ + (kk) + (c >> 6) * 8,                     \
                &vtl[0][slot][0][0][0] + c * 8);                                          \
        async16(Vbase + (size_t)(c & 63) * SEQ + (kk) + 64 + (c >> 6) * 8,                \
                &vtl[1][slot][0][0][0] + c * 8);                                          \
    }

    STAGE(0, 0)

    for (int i = 0; i < 16; ++i) {
        const int slot = i & 1;
        __syncthreads();                        // both parity tiles of phase i ready
        if (i < 15) STAGE(slot ^ 1, (i + 1) * 128)

        // S^T: D[m=key][n=q]
        floatx16 s0, s1;
#pragma unroll
        for (int r = 0; r < 16; r++) { s0[r] = 0.f; s1[r] = 0.f; }
#pragma unroll
        for (int ks = 0; ks < 4; ks++) {
            const short8 a0 = *(const short8*)&kt[par][slot][2*ks + hi][l31][0];
            const short8 a1 = *(const short8*)&kt[par][slot][2*ks + hi][32 + l31][0];
            s0 = __builtin_amdgcn_mfma_f32_32x32x16_bf16(a0, qf[ks], s0, 0, 0, 0);
            s1 = __builtin_amdgcn_mfma_f32_32x32x16_bf16(a1, qf[ks], s1, 0, 0, 0);
        }

        // p = 2^s (raw v_exp_f32), per-lane rsum, pack adjacent-k pairs
        unsigned p[16];
#pragma unroll
        for (int i2 = 0; i2 < 8; i2++) {
            const float a0 = EXP2(s0[2*i2]), b0 = EXP2(s0[2*i2+1]);
            const float a1 = EXP2(s1[2*i2]), b1 = EXP2(s1[2*i2+1]);
            rsum += (a0 + b0) + (a1 + b1);
            p[i2]     = pk2(a0, b0);
            p[8 + i2] = pk2(a1, b1);
        }

        // build A-fragments: one shuffle serves both slots of a (pa,pb) pair
        unsigned fu[4][4];
#pragma unroll
        for (int g = 0; g < 4; g++) {
            const int base = (g >> 1) * 8 + (g & 1) * 4;  // 0,4,8,12
#pragma unroll
            for (int j = 0; j < 2; j++) {
                const unsigned pa = p[base + j], pb = p[base + j + 2];
                const unsigned pre = hi ? pa : pb;
                const unsigned sw = (unsigned)__shfl_xor((int)pre, 32, 64);
                fu[g][j]     = hi ? sw : pa;
                fu[g][j + 2] = hi ? pb : sw;
            }
        }

        // O += P V
#pragma unroll
        for (int ks = 0; ks < 4; ks++) {
            union { unsigned u[4]; short8 s; } pf;
            pf.u[0] = fu[ks][0]; pf.u[1] = fu[ks][1]; pf.u[2] = fu[ks][2]; pf.u[3] = fu[ks][3];
            const short8 v0 = *(const short8*)&vtl[par][slot][2*ks + hi][l31][0];
            const short8 v1 = *(const short8*)&vtl[par][slot][2*ks + hi][32 + l31][0];
            o0 = __builtin_amdgcn_mfma_f32_32x32x16_bf16(pf.s, v0, o0, 0, 0, 0);
            o1 = __builtin_amdgcn_mfma_f32_32x32x16_bf16(pf.s, v1, o1, 0, 0, 0);
        }
    }
#undef STAGE

    // own-wave key-half combine
    rsum += __shfl_xor(rsum, 32, 64);

    // parity merge via LDS (reuse staging buffers; all compute done after barrier)
    float* mO = (float*)&kt[0][0][0][0][0];     // [4][32][64]
    float* rS = (float*)&vtl[0][0][0][0][0];    // [4][32]
    __syncthreads();
    if (par == 1) {
#pragma unroll
        for (int r = 0; r < 16; r++) {
            const int qr = (r & 3) + 8 * (r >> 2) + (hi ? 4 : 0);
            mO[(qg*32 + qr)*64 + l31]      = o0[r];
            mO[(qg*32 + qr)*64 + 32 + l31] = o1[r];
        }
        if (!hi) rS[qg*32 + l31] = rsum;
    }
    __syncthreads();
    if (par == 0) {
        const float inv = 1.0f / (rsum + rS[qg*32 + l31]);  // lane l: q-row l31
        const int b = bh >> 4, h = bh & 15;
#pragma unroll
        for (int r = 0; r < 16; r++) {
            const int qr = (r & 3) + 8 * (r >> 2) + (hi ? 4 : 0);
            const float invr = __shfl(inv, qr, 64);
            const float v0 = o0[r] + mO[(qg*32 + qr)*64 + l31];
            const float v1 = o1[r] + mO[(qg*32 + qr)*64 + 32 + l31];
            const int seq = q0 + qg*32 + qr;
            short* dst = Ob + ((size_t)(b * SEQ + seq)) * D_MODEL + h * HDIM + l31;
            dst[0]  = f2bf(v0 * invr);
            dst[32] = f2bf(v1 * invr);
        }
    }
}

// ---------------------------------------------------------------- launch
extern "C" void kernel_launch(void* const* d_in, const int* in_sizes, int n_in,
                              void* d_out, int out_size, void* d_ws, size_t ws_size,
                              hipStream_t stream)
{
    const float* x  = (const float*)d_in[0];
    const float* Wq = (const float*)d_in[1];
    const float* bq = (const float*)d_in[2];
    const float* Wk = (const float*)d_in[3];
    const float* bk = (const float*)d_in[4];
    const float* Wv = (const float*)d_in[5];
    const float* bv = (const float*)d_in[6];
    const float* Wo = (const float*)d_in[7];
    const float* bo = (const float*)d_in[8];
    float* out = (float*)d_out;

    short* ws = (short*)d_ws;
    const size_t NX = (size_t)MTOT * D_MODEL;     // 4194304
    const size_t NW = (size_t)D_MODEL * D_MODEL;  // 1048576
    short* xb  = ws;
    short* wqb = xb  + NX;
    short* wkb = wqb + NW;
    short* wvb = wkb + NW;
    short* wob = wvb + NW;
    short* Qb  = wob + NW;
    short* Kb  = Qb  + NX;
    short* Vt  = Kb  + NX;   // V stored transposed directly by qkv_gemm
    short* Ob  = Vt  + NX;

    cast_all_kernel<<<dim3(4096), 256, 0, stream>>>(x, Wq, Wk, Wv, Wo, xb, wqb, wkb, wvb, wob);
    qkv_gemm_kernel<<<dim3(8, 32, 3), 256, 0, stream>>>(xb, wqb, wkb, wvb, bq, bk, bv, Qb, Kb, Vt);
    attn_kernel<<<dim3(16, 32), 512, 0, stream>>>(Qb, Kb, Vt, Ob);
    out_gemm_kernel<<<dim3(16, 32), 256, 0, stream>>>(Ob, wob, bo, out);
}